// Round 3
// baseline (408.645 us; speedup 1.0000x reference)
//
#include <hip/hip_runtime.h>

typedef short bf16x8 __attribute__((ext_vector_type(8)));
typedef float f32x4 __attribute__((ext_vector_type(4)));

__device__ __forceinline__ unsigned short f2bf(float f) {
    unsigned int u = __builtin_bit_cast(unsigned int, f);
    u = (u + 0x7FFFu + ((u >> 16) & 1u)) >> 16;
    return (unsigned short)u;
}
__device__ __forceinline__ float bf2f(unsigned short h) {
    unsigned int u = ((unsigned int)h) << 16;
    return __builtin_bit_cast(float, u);
}

// ---------------------------------------------------------------------------
// Prep: permute x (B,T,N,Dm) -> Xbf rows r = bn*128+t, bn = b*64+n; fp32->bf16
__global__ __launch_bounds__(256) void k_prep_x(const float* __restrict__ x,
                                                unsigned int* __restrict__ Xbf2) {
    int tid = blockIdx.x * 256 + threadIdx.x;
    int c4 = tid & 63;      // group of 4 columns
    int r  = tid >> 6;      // output row
    int t = r & 127, bn = r >> 7;
    int n = bn & 63, b = bn >> 6;
    const float4 v = *((const float4*)(x + ((((size_t)(b * 128 + t)) * 64 + n) << 8)) + c4);
    uint2 o;
    o.x = (unsigned int)f2bf(v.x) | ((unsigned int)f2bf(v.y) << 16);
    o.y = (unsigned int)f2bf(v.z) | ((unsigned int)f2bf(v.w) << 16);
    *((uint2*)(Xbf2 + ((size_t)r << 7)) + c4) = o;
}

// Generic fp32 -> bf16 convert, 4 elements/thread (count % 4 == 0).
__global__ __launch_bounds__(256) void k_f2bf(const float* __restrict__ in,
                                              unsigned int* __restrict__ out, int n4) {
    int tid = blockIdx.x * 256 + threadIdx.x;
    if (tid >= n4) return;
    float4 v = ((const float4*)in)[tid];
    uint2 o;
    o.x = (unsigned int)f2bf(v.x) | ((unsigned int)f2bf(v.y) << 16);
    o.y = (unsigned int)f2bf(v.z) | ((unsigned int)f2bf(v.w) << 16);
    ((uint2*)out)[tid] = o;
}

// ---------------------------------------------------------------------------
// GEMM1: xz[16384 x 1024] = Xbf[16384 x 256] @ W_in_bf[1024 x 256]^T
__global__ __launch_bounds__(256, 2) void k_gemm1(const unsigned short* __restrict__ A,
                                                  const unsigned short* __restrict__ Bw,
                                                  unsigned short* __restrict__ xp,
                                                  unsigned short* __restrict__ z) {
    const int w = threadIdx.x >> 6, l = threadIdx.x & 63;
    const int lr = l & 15, lg = l >> 4;
    const int row0 = blockIdx.x * 256 + w * 64;
    const int n0 = blockIdx.y * 64;
    f32x4 acc[4][4] = {};
    for (int k0 = 0; k0 < 256; k0 += 32) {
        const int ka = k0 + lg * 8;
        bf16x8 a[4], b[4];
        #pragma unroll
        for (int mi = 0; mi < 4; ++mi)
            a[mi] = *(const bf16x8*)(A + (size_t)(row0 + mi * 16 + lr) * 256 + ka);
        #pragma unroll
        for (int ni = 0; ni < 4; ++ni)
            b[ni] = *(const bf16x8*)(Bw + (size_t)(n0 + ni * 16 + lr) * 256 + ka);
        #pragma unroll
        for (int mi = 0; mi < 4; ++mi)
            #pragma unroll
            for (int ni = 0; ni < 4; ++ni)
                acc[mi][ni] = __builtin_amdgcn_mfma_f32_16x16x32_bf16(a[mi], b[ni], acc[mi][ni], 0, 0, 0);
    }
    const bool isz = (n0 >= 512);
    unsigned short* dst = isz ? z : xp;
    const int c0 = isz ? (n0 - 512) : n0;
    #pragma unroll
    for (int mi = 0; mi < 4; ++mi)
        #pragma unroll
        for (int r = 0; r < 4; ++r) {
            const int row = row0 + mi * 16 + lg * 4 + r;
            #pragma unroll
            for (int ni = 0; ni < 4; ++ni)
                dst[(size_t)row * 512 + c0 + ni * 16 + lr] = f2bf(acc[mi][ni][r]);
        }
}

// ---------------------------------------------------------------------------
// Depthwise causal conv(4) + bias + SiLU, fully parallel over (bn, t, d-pair).
__global__ __launch_bounds__(256) void k_conv(const unsigned short* __restrict__ xp,
                                              const float* __restrict__ Wc,
                                              const float* __restrict__ bcv,
                                              unsigned int* __restrict__ ub2) {
    int tid = blockIdx.x * 256 + threadIdx.x;
    int d2 = tid & 255, r = tid >> 8;   // r = bn*128 + t
    int t = r & 127, bn = r >> 7;
    int d = d2 << 1;
    const unsigned short* src = xp + (size_t)bn * 65536 + d;
    f32x4 wa = *(const f32x4*)(Wc + d * 4);
    f32x4 wb = *(const f32x4*)(Wc + d * 4 + 4);
    float a0 = bcv[d], a1 = bcv[d + 1];
    #pragma unroll
    for (int k = 0; k < 4; ++k) {
        int tt = t - 3 + k;
        if (tt >= 0) {
            unsigned int p = *(const unsigned int*)(src + (size_t)tt * 512);
            a0 += bf2f((unsigned short)(p & 0xFFFFu)) * wa[k];
            a1 += bf2f((unsigned short)(p >> 16)) * wb[k];
        }
    }
    float u0 = a0 / (1.f + __expf(-a0));
    float u1 = a1 / (1.f + __expf(-a1));
    ub2[((size_t)bn * 65536 + (size_t)t * 512 + d) >> 1] =
        (unsigned int)f2bf(u0) | ((unsigned int)f2bf(u1) << 16);
}

// ---------------------------------------------------------------------------
// x_dbl[16384 x 48] = u_bf[16384 x 512] @ W_xproj_bf[48 x 512]^T  (fp32 out)
__global__ __launch_bounds__(256, 2) void k_xproj(const unsigned short* __restrict__ U,
                                                  const unsigned short* __restrict__ Wb,
                                                  float* __restrict__ xdbl) {
    const int w = threadIdx.x >> 6, l = threadIdx.x & 63;
    const int lr = l & 15, lg = l >> 4;
    const int row0 = blockIdx.x * 64 + w * 16;
    f32x4 acc[3] = {};
    for (int k0 = 0; k0 < 512; k0 += 32) {
        const int ka = k0 + lg * 8;
        bf16x8 a = *(const bf16x8*)(U + (size_t)(row0 + lr) * 512 + ka);
        bf16x8 b[3];
        #pragma unroll
        for (int ni = 0; ni < 3; ++ni)
            b[ni] = *(const bf16x8*)(Wb + (size_t)(ni * 16 + lr) * 512 + ka);
        #pragma unroll
        for (int ni = 0; ni < 3; ++ni)
            acc[ni] = __builtin_amdgcn_mfma_f32_16x16x32_bf16(a, b[ni], acc[ni], 0, 0, 0);
    }
    #pragma unroll
    for (int r = 0; r < 4; ++r) {
        const int row = row0 + lg * 4 + r;
        #pragma unroll
        for (int ni = 0; ni < 3; ++ni)
            xdbl[(size_t)row * 48 + ni * 16 + lr] = acc[ni][r];
    }
}

// ---------------------------------------------------------------------------
// dt = softplus(dt_raw @ W_dt^T + b_dt), fully parallel. One thread per (r, d).
__global__ __launch_bounds__(256) void k_dt(const float* __restrict__ xdbl,
                                            const float* __restrict__ W_dt,
                                            const float* __restrict__ b_dt,
                                            _Float16* __restrict__ dtb) {
    int tid = blockIdx.x * 256 + threadIdx.x;
    int d = tid & 511, r = tid >> 9;
    const f32x4* xr = (const f32x4*)(xdbl + (size_t)r * 48);
    const f32x4* wd = (const f32x4*)(W_dt + d * 16);
    float dl = b_dt[d];
    #pragma unroll
    for (int k = 0; k < 4; ++k) {
        f32x4 xv = xr[k], wv = wd[k];
        dl += xv[0] * wv[0] + xv[1] * wv[1] + xv[2] * wv[2] + xv[3] * wv[3];
    }
    float dt = (dl > 20.f) ? dl : log1pf(__expf(dl));
    dtb[(size_t)r * 512 + d] = (_Float16)dt;
}

// ---------------------------------------------------------------------------
// Chunked parallel selective scan.
// Block = 1024 threads = 8 chunks(T) x 32 d x 4 state-lanes; one (bn, d-group).
// Grid = 128 bn x 16 d-groups = 2048 blocks.
// Linear recurrence h_t = dA_t h_{t-1} + b_t composed associatively:
//   (P,H) o (P',H') = (P P', H + P H')
// Pass1: per-chunk local scan (h0=0) + product P. Hillis-Steele over 8 chunks
// in LDS gives exact chunk entry states. Pass2: rescan with true h0, emit y.
__global__ __launch_bounds__(1024) void k_scan(const _Float16* __restrict__ dtb,
                                               const float* __restrict__ xdbl,
                                               const unsigned short* __restrict__ ub,
                                               const unsigned short* __restrict__ zb,
                                               const float* __restrict__ A_log,
                                               const float* __restrict__ Dp,
                                               unsigned short* __restrict__ yb) {
    __shared__ float bc[128][32];          // [t][ B(0..15) | C(16..31) ]
    __shared__ f32x4 combP[8][32][4];
    __shared__ f32x4 combH[8][32][4];
    const int bn = blockIdx.x >> 4;
    const int d0 = (blockIdx.x & 15) * 32;
    {   // stage B,C for this bn: 128 rows x 32 floats, one f32x4 per thread
        const float* src = xdbl + (size_t)(bn * 128) * 48 + 16;
        int row = threadIdx.x >> 3, c4 = threadIdx.x & 7;
        *(f32x4*)(&bc[row][c4 * 4]) = *(const f32x4*)(src + row * 48 + c4 * 4);
    }
    const int sub = threadIdx.x & 3;          // state quad
    const int dg  = (threadIdx.x >> 2) & 31;  // d within group
    const int c   = threadIdx.x >> 7;         // chunk (wave-uniform)
    const int d   = d0 + dg;
    const int s0  = sub * 4;
    float A[4];
    {
        f32x4 al = *(const f32x4*)(A_log + d * 16 + s0);
        #pragma unroll
        for (int j = 0; j < 4; ++j) A[j] = -__expf(al[j]);
    }
    const _Float16* dtp = dtb + (size_t)(bn * 128) * 512 + d;
    const unsigned short* up = ub + (size_t)bn * 65536 + d;
    const unsigned short* zp = zb + (size_t)bn * 65536 + d;
    unsigned short* yp = yb + (size_t)bn * 65536 + d;
    const int t0 = c * 16;
    __syncthreads();
    // --- pass 1: local scan with h0=0, track P = prod(dA) ---
    f32x4 p = {1.f, 1.f, 1.f, 1.f}, h = {};
    for (int i = 0; i < 16; ++i) {
        const int t = t0 + i;
        float dtv = (float)dtp[t * 512];
        float uv  = bf2f(up[t * 512]);
        f32x4 Bv = *(const f32x4*)(&bc[t][s0]);
        float du = dtv * uv;
        #pragma unroll
        for (int j = 0; j < 4; ++j) {
            float dA = __expf(dtv * A[j]);
            h[j] = h[j] * dA + du * Bv[j];
            p[j] *= dA;
        }
    }
    combP[c][dg][sub] = p;
    combH[c][dg][sub] = h;
    __syncthreads();
    // --- Hillis-Steele inclusive scan over chunks (c is wave-uniform) ---
    #pragma unroll
    for (int s = 1; s < 8; s <<= 1) {
        f32x4 pp = {}, hp = {};
        if (c >= s) { pp = combP[c - s][dg][sub]; hp = combH[c - s][dg][sub]; }
        __syncthreads();
        if (c >= s) {
            #pragma unroll
            for (int j = 0; j < 4; ++j) { h[j] += p[j] * hp[j]; p[j] *= pp[j]; }
            combP[c][dg][sub] = p;
            combH[c][dg][sub] = h;
        }
        __syncthreads();
    }
    f32x4 hh = {};
    if (c > 0) hh = combH[c - 1][dg][sub];
    // --- pass 2: rescan from true entry state, emit y ---
    const float dpar = Dp[d];
    for (int i = 0; i < 16; ++i) {
        const int t = t0 + i;
        float dtv = (float)dtp[t * 512];
        float uv  = bf2f(up[t * 512]);
        float zv  = bf2f(zp[t * 512]);
        f32x4 Bv = *(const f32x4*)(&bc[t][s0]);
        f32x4 Cv = *(const f32x4*)(&bc[t][16 + s0]);
        float du = dtv * uv;
        float y = 0.f;
        #pragma unroll
        for (int j = 0; j < 4; ++j) {
            float dA = __expf(dtv * A[j]);
            hh[j] = hh[j] * dA + du * Bv[j];
            y += hh[j] * Cv[j];
        }
        y += __shfl_xor(y, 1);
        y += __shfl_xor(y, 2);
        if (sub == 0) {
            float yf = (y + uv * dpar) * (zv / (1.f + __expf(-zv)));
            yp[t * 512] = f2bf(yf);
        }
    }
}

// ---------------------------------------------------------------------------
// out = LayerNorm( y_bf[16384 x 512] @ W_out_bf[256 x 512]^T ) with permuted store.
__global__ __launch_bounds__(256, 2) void k_out_ln(const unsigned short* __restrict__ Y,
                                                   const unsigned short* __restrict__ Wb,
                                                   const float* __restrict__ gamma,
                                                   const float* __restrict__ beta,
                                                   float* __restrict__ out) {
    __shared__ float s_sum[32], s_sq[32];
    const int w = threadIdx.x >> 6, l = threadIdx.x & 63;
    const int lr = l & 15, lg = l >> 4;
    const int row0 = blockIdx.x * 32;
    const int n0 = w * 64;
    f32x4 acc[2][4] = {};
    for (int k0 = 0; k0 < 512; k0 += 32) {
        const int ka = k0 + lg * 8;
        bf16x8 a[2], b[4];
        #pragma unroll
        for (int mi = 0; mi < 2; ++mi)
            a[mi] = *(const bf16x8*)(Y + (size_t)(row0 + mi * 16 + lr) * 512 + ka);
        #pragma unroll
        for (int ni = 0; ni < 4; ++ni)
            b[ni] = *(const bf16x8*)(Wb + (size_t)(n0 + ni * 16 + lr) * 512 + ka);
        #pragma unroll
        for (int mi = 0; mi < 2; ++mi)
            #pragma unroll
            for (int ni = 0; ni < 4; ++ni)
                acc[mi][ni] = __builtin_amdgcn_mfma_f32_16x16x32_bf16(a[mi], b[ni], acc[mi][ni], 0, 0, 0);
    }
    if (threadIdx.x < 32) { s_sum[threadIdx.x] = 0.f; s_sq[threadIdx.x] = 0.f; }
    __syncthreads();
    #pragma unroll
    for (int mi = 0; mi < 2; ++mi)
        #pragma unroll
        for (int r = 0; r < 4; ++r) {
            float s = 0.f, q = 0.f;
            #pragma unroll
            for (int ni = 0; ni < 4; ++ni) { float v = acc[mi][ni][r]; s += v; q += v * v; }
            #pragma unroll
            for (int m = 1; m < 16; m <<= 1) { s += __shfl_xor(s, m, 64); q += __shfl_xor(q, m, 64); }
            if (lr == 0) {
                atomicAdd(&s_sum[mi * 16 + lg * 4 + r], s);
                atomicAdd(&s_sq[mi * 16 + lg * 4 + r], q);
            }
        }
    __syncthreads();
    float g[4], be[4];
    #pragma unroll
    for (int ni = 0; ni < 4; ++ni) {
        g[ni] = gamma[n0 + ni * 16 + lr];
        be[ni] = beta[n0 + ni * 16 + lr];
    }
    #pragma unroll
    for (int mi = 0; mi < 2; ++mi)
        #pragma unroll
        for (int r = 0; r < 4; ++r) {
            const int rl = mi * 16 + lg * 4 + r;
            const int row = row0 + rl;
            const float mu = s_sum[rl] * (1.f / 256.f);
            const float var = s_sq[rl] * (1.f / 256.f) - mu * mu;
            const float rs = rsqrtf(var + 1e-5f);
            const int t = row & 127, bn = row >> 7;
            const int nn = bn & 63, bb = bn >> 6;
            float* orow = out + ((((size_t)(bb * 128 + t)) * 64 + nn) << 8);
            #pragma unroll
            for (int ni = 0; ni < 4; ++ni)
                orow[n0 + ni * 16 + lr] = (acc[mi][ni][r] - mu) * rs * g[ni] + be[ni];
        }
}

// ---------------------------------------------------------------------------
extern "C" void kernel_launch(void* const* d_in, const int* in_sizes, int n_in,
                              void* d_out, int out_size, void* d_ws, size_t ws_size,
                              hipStream_t stream) {
    const float* x      = (const float*)d_in[0];
    const float* W_in   = (const float*)d_in[1];
    const float* W_conv = (const float*)d_in[2];
    const float* b_conv = (const float*)d_in[3];
    const float* W_xprj = (const float*)d_in[4];
    const float* W_dt   = (const float*)d_in[5];
    const float* b_dt   = (const float*)d_in[6];
    const float* A_log  = (const float*)d_in[7];
    const float* D_par  = (const float*)d_in[8];
    const float* W_out  = (const float*)d_in[9];
    const float* gamma  = (const float*)d_in[10];
    const float* beta   = (const float*)d_in[11];
    float* out = (float*)d_out;

    char* ws = (char*)d_ws;
    size_t off = 0;
    auto alloc = [&](size_t bytes) -> void* {
        void* p = ws + off;
        off += (bytes + 255) & ~(size_t)255;
        return p;
    };
    // --- overlay region: dead after k_xproj; dtb aliases it ---
    unsigned short* Xbf   = (unsigned short*)alloc(16384ull * 256 * 2);  // 8.4 MB
    unsigned short* Winb  = (unsigned short*)alloc(1024ull * 256 * 2);
    unsigned short* Wxpb  = (unsigned short*)alloc(48ull * 512 * 2);
    unsigned short* xp    = (unsigned short*)alloc(16384ull * 512 * 2);  // 16.8 MB
    // --- live to the end ---
    unsigned short* Woutb = (unsigned short*)alloc(256ull * 512 * 2);
    unsigned short* zb    = (unsigned short*)alloc(16384ull * 512 * 2);
    unsigned short* ub    = (unsigned short*)alloc(16384ull * 512 * 2);
    float*          xdbl  = (float*)alloc(16384ull * 48 * 4);
    unsigned short* yb    = (unsigned short*)alloc(16384ull * 512 * 2);
    _Float16*       dtb   = (_Float16*)(ws);  // alias over Xbf..xp (dead by then)
    if (off > ws_size) return;

    k_prep_x<<<4096, 256, 0, stream>>>(x, (unsigned int*)Xbf);
    k_f2bf<<<256, 256, 0, stream>>>(W_in, (unsigned int*)Winb, 65536);
    k_f2bf<<<24, 256, 0, stream>>>(W_xprj, (unsigned int*)Wxpb, 6144);
    k_f2bf<<<128, 256, 0, stream>>>(W_out, (unsigned int*)Woutb, 32768);
    k_gemm1<<<dim3(64, 16), 256, 0, stream>>>(Xbf, Winb, xp, zb);
    k_conv<<<16384, 256, 0, stream>>>(xp, W_conv, b_conv, (unsigned int*)ub);
    k_xproj<<<256, 256, 0, stream>>>(ub, Wxpb, xdbl);
    k_dt<<<32768, 256, 0, stream>>>(xdbl, W_dt, b_dt, dtb);
    k_scan<<<2048, 1024, 0, stream>>>(dtb, xdbl, ub, zb, A_log, D_par, yb);
    k_out_ln<<<512, 256, 0, stream>>>(yb, Woutb, gamma, beta, out);
}

// Round 4
// 242.505 us; speedup vs baseline: 1.6851x; 1.6851x over previous
//
#include <hip/hip_runtime.h>

typedef short bf16x8 __attribute__((ext_vector_type(8)));
typedef float f32x4 __attribute__((ext_vector_type(4)));

__device__ __forceinline__ unsigned short f2bf(float f) {
    unsigned int u = __builtin_bit_cast(unsigned int, f);
    u = (u + 0x7FFFu + ((u >> 16) & 1u)) >> 16;
    return (unsigned short)u;
}
__device__ __forceinline__ float bf2f(unsigned short h) {
    unsigned int u = ((unsigned int)h) << 16;
    return __builtin_bit_cast(float, u);
}

// ---------------------------------------------------------------------------
// Prep: permute x (B,T,N,Dm) -> Xbf rows r = bn*128+t, bn = b*64+n; fp32->bf16
__global__ __launch_bounds__(256) void k_prep_x(const float* __restrict__ x,
                                                unsigned int* __restrict__ Xbf2) {
    int tid = blockIdx.x * 256 + threadIdx.x;
    int c4 = tid & 63;      // group of 4 columns
    int r  = tid >> 6;      // output row
    int t = r & 127, bn = r >> 7;
    int n = bn & 63, b = bn >> 6;
    const float4 v = *((const float4*)(x + ((((size_t)(b * 128 + t)) * 64 + n) << 8)) + c4);
    uint2 o;
    o.x = (unsigned int)f2bf(v.x) | ((unsigned int)f2bf(v.y) << 16);
    o.y = (unsigned int)f2bf(v.z) | ((unsigned int)f2bf(v.w) << 16);
    *((uint2*)(Xbf2 + ((size_t)r << 7)) + c4) = o;
}

// Generic fp32 -> bf16 convert, 4 elements/thread (count % 4 == 0).
__global__ __launch_bounds__(256) void k_f2bf(const float* __restrict__ in,
                                              unsigned int* __restrict__ out, int n4) {
    int tid = blockIdx.x * 256 + threadIdx.x;
    if (tid >= n4) return;
    float4 v = ((const float4*)in)[tid];
    uint2 o;
    o.x = (unsigned int)f2bf(v.x) | ((unsigned int)f2bf(v.y) << 16);
    o.y = (unsigned int)f2bf(v.z) | ((unsigned int)f2bf(v.w) << 16);
    ((uint2*)out)[tid] = o;
}

// ---------------------------------------------------------------------------
// GEMM1: xz[16384 x 1024] = Xbf[16384 x 256] @ W_in_bf[1024 x 256]^T
__global__ __launch_bounds__(256, 2) void k_gemm1(const unsigned short* __restrict__ A,
                                                  const unsigned short* __restrict__ Bw,
                                                  unsigned short* __restrict__ xp,
                                                  unsigned short* __restrict__ z) {
    const int w = threadIdx.x >> 6, l = threadIdx.x & 63;
    const int lr = l & 15, lg = l >> 4;
    const int row0 = blockIdx.x * 256 + w * 64;
    const int n0 = blockIdx.y * 64;
    f32x4 acc[4][4] = {};
    for (int k0 = 0; k0 < 256; k0 += 32) {
        const int ka = k0 + lg * 8;
        bf16x8 a[4], b[4];
        #pragma unroll
        for (int mi = 0; mi < 4; ++mi)
            a[mi] = *(const bf16x8*)(A + (size_t)(row0 + mi * 16 + lr) * 256 + ka);
        #pragma unroll
        for (int ni = 0; ni < 4; ++ni)
            b[ni] = *(const bf16x8*)(Bw + (size_t)(n0 + ni * 16 + lr) * 256 + ka);
        #pragma unroll
        for (int mi = 0; mi < 4; ++mi)
            #pragma unroll
            for (int ni = 0; ni < 4; ++ni)
                acc[mi][ni] = __builtin_amdgcn_mfma_f32_16x16x32_bf16(a[mi], b[ni], acc[mi][ni], 0, 0, 0);
    }
    const bool isz = (n0 >= 512);
    unsigned short* dst = isz ? z : xp;
    const int c0 = isz ? (n0 - 512) : n0;
    #pragma unroll
    for (int mi = 0; mi < 4; ++mi)
        #pragma unroll
        for (int r = 0; r < 4; ++r) {
            const int row = row0 + mi * 16 + lg * 4 + r;
            #pragma unroll
            for (int ni = 0; ni < 4; ++ni)
                dst[(size_t)row * 512 + c0 + ni * 16 + lr] = f2bf(acc[mi][ni][r]);
        }
}

// ---------------------------------------------------------------------------
// Depthwise causal conv(4) + bias + SiLU, fully parallel over (bn, t, d-pair).
__global__ __launch_bounds__(256) void k_conv(const unsigned short* __restrict__ xp,
                                              const float* __restrict__ Wc,
                                              const float* __restrict__ bcv,
                                              unsigned int* __restrict__ ub2) {
    int tid = blockIdx.x * 256 + threadIdx.x;
    int d2 = tid & 255, r = tid >> 8;   // r = bn*128 + t
    int t = r & 127, bn = r >> 7;
    int d = d2 << 1;
    const unsigned short* src = xp + (size_t)bn * 65536 + d;
    f32x4 wa = *(const f32x4*)(Wc + d * 4);
    f32x4 wb = *(const f32x4*)(Wc + d * 4 + 4);
    float a0 = bcv[d], a1 = bcv[d + 1];
    #pragma unroll
    for (int k = 0; k < 4; ++k) {
        int tt = t - 3 + k;
        if (tt >= 0) {
            unsigned int p = *(const unsigned int*)(src + (size_t)tt * 512);
            a0 += bf2f((unsigned short)(p & 0xFFFFu)) * wa[k];
            a1 += bf2f((unsigned short)(p >> 16)) * wb[k];
        }
    }
    float u0 = a0 / (1.f + __expf(-a0));
    float u1 = a1 / (1.f + __expf(-a1));
    ub2[((size_t)bn * 65536 + (size_t)t * 512 + d) >> 1] =
        (unsigned int)f2bf(u0) | ((unsigned int)f2bf(u1) << 16);
}

// ---------------------------------------------------------------------------
// x_dbl[16384 x 48] = u_bf[16384 x 512] @ W_xproj_bf[48 x 512]^T  (fp32 out)
__global__ __launch_bounds__(256, 2) void k_xproj(const unsigned short* __restrict__ U,
                                                  const unsigned short* __restrict__ Wb,
                                                  float* __restrict__ xdbl) {
    const int w = threadIdx.x >> 6, l = threadIdx.x & 63;
    const int lr = l & 15, lg = l >> 4;
    const int row0 = blockIdx.x * 64 + w * 16;
    f32x4 acc[3] = {};
    for (int k0 = 0; k0 < 512; k0 += 32) {
        const int ka = k0 + lg * 8;
        bf16x8 a = *(const bf16x8*)(U + (size_t)(row0 + lr) * 512 + ka);
        bf16x8 b[3];
        #pragma unroll
        for (int ni = 0; ni < 3; ++ni)
            b[ni] = *(const bf16x8*)(Wb + (size_t)(ni * 16 + lr) * 512 + ka);
        #pragma unroll
        for (int ni = 0; ni < 3; ++ni)
            acc[ni] = __builtin_amdgcn_mfma_f32_16x16x32_bf16(a, b[ni], acc[ni], 0, 0, 0);
    }
    #pragma unroll
    for (int r = 0; r < 4; ++r) {
        const int row = row0 + lg * 4 + r;
        #pragma unroll
        for (int ni = 0; ni < 3; ++ni)
            xdbl[(size_t)row * 48 + ni * 16 + lr] = acc[ni][r];
    }
}

// ---------------------------------------------------------------------------
// dt = softplus(dt_raw @ W_dt^T + b_dt), fully parallel. One thread per (r, d).
__global__ __launch_bounds__(256) void k_dt(const float* __restrict__ xdbl,
                                            const float* __restrict__ W_dt,
                                            const float* __restrict__ b_dt,
                                            _Float16* __restrict__ dtb) {
    int tid = blockIdx.x * 256 + threadIdx.x;
    int d = tid & 511, r = tid >> 9;
    const f32x4* xr = (const f32x4*)(xdbl + (size_t)r * 48);
    const f32x4* wd = (const f32x4*)(W_dt + d * 16);
    float dl = b_dt[d];
    #pragma unroll
    for (int k = 0; k < 4; ++k) {
        f32x4 xv = xr[k], wv = wd[k];
        dl += xv[0] * wv[0] + xv[1] * wv[1] + xv[2] * wv[2] + xv[3] * wv[3];
    }
    float dt = (dl > 20.f) ? dl : log1pf(__expf(dl));
    dtb[(size_t)r * 512 + d] = (_Float16)dt;
}

// ---------------------------------------------------------------------------
// Chunked parallel selective scan, spill-proof sizing.
// Block = 512 threads = 4 chunks(T=32 each) x 32 d x 4 state-lanes.
// Grid = 128 bn x 16 d-groups = 2048 blocks.
// (P,H) o (P',H') = (P P', H + P H'); pass1 local scan + P, 2-step
// Hillis-Steele over 4 chunks in LDS, pass2 rescan from true entry state.
// All-scalar state to stay under 64 VGPRs (R3 lesson: spills = 432 MB scratch).
__global__ __launch_bounds__(512, 8) void k_scan(const _Float16* __restrict__ dtb,
                                                 const float* __restrict__ xdbl,
                                                 const unsigned short* __restrict__ ub,
                                                 const unsigned short* __restrict__ zb,
                                                 const float* __restrict__ A_log,
                                                 const float* __restrict__ Dp,
                                                 unsigned short* __restrict__ yb) {
    __shared__ float bc[128][32];     // [t][ B(0..15) | C(16..31) ]
    __shared__ float cP[4][32][16];   // [chunk][dg][state]
    __shared__ float cH[4][32][16];
    const int bn = blockIdx.x >> 4;
    const int d0 = (blockIdx.x & 15) * 32;
    {   // stage B,C for this bn: 128 rows x 8 f32x4, 512 threads x 2 rounds
        const float* src = xdbl + (size_t)(bn * 128) * 48 + 16;
        #pragma unroll
        for (int k = 0; k < 2; ++k) {
            int li = threadIdx.x + k * 512;
            int row = li >> 3, c4 = li & 7;
            *(f32x4*)(&bc[row][c4 * 4]) = *(const f32x4*)(src + row * 48 + c4 * 4);
        }
    }
    const int sub = threadIdx.x & 3;          // state quad
    const int dg  = (threadIdx.x >> 2) & 31;  // d within group
    const int c   = threadIdx.x >> 7;         // chunk (wave-uniform: wave>>1)
    const int d   = d0 + dg;
    const int s0  = sub * 4;
    float A0, A1, A2, A3;
    {
        f32x4 al = *(const f32x4*)(A_log + d * 16 + s0);
        A0 = -__expf(al[0]); A1 = -__expf(al[1]);
        A2 = -__expf(al[2]); A3 = -__expf(al[3]);
    }
    const _Float16* dtp = dtb + (size_t)(bn * 128) * 512 + d;
    const unsigned short* up = ub + (size_t)bn * 65536 + d;
    const unsigned short* zp = zb + (size_t)bn * 65536 + d;
    unsigned short* yp = yb + (size_t)bn * 65536 + d;
    const int t0 = c * 32;
    __syncthreads();
    // --- pass 1: local scan (h0=0), track P = prod(dA). No C/y/z work. ---
    float p0 = 1.f, p1 = 1.f, p2 = 1.f, p3 = 1.f;
    float h0 = 0.f, h1 = 0.f, h2 = 0.f, h3 = 0.f;
    for (int i = 0; i < 32; ++i) {
        const int t = t0 + i;
        float dtv = (float)dtp[t * 512];
        float du = dtv * bf2f(up[t * 512]);
        float e0 = __expf(dtv * A0), e1 = __expf(dtv * A1);
        float e2 = __expf(dtv * A2), e3 = __expf(dtv * A3);
        h0 = h0 * e0 + du * bc[t][s0 + 0]; p0 *= e0;
        h1 = h1 * e1 + du * bc[t][s0 + 1]; p1 *= e1;
        h2 = h2 * e2 + du * bc[t][s0 + 2]; p2 *= e2;
        h3 = h3 * e3 + du * bc[t][s0 + 3]; p3 *= e3;
    }
    cP[c][dg][s0 + 0] = p0; cP[c][dg][s0 + 1] = p1;
    cP[c][dg][s0 + 2] = p2; cP[c][dg][s0 + 3] = p3;
    cH[c][dg][s0 + 0] = h0; cH[c][dg][s0 + 1] = h1;
    cH[c][dg][s0 + 2] = h2; cH[c][dg][s0 + 3] = h3;
    __syncthreads();
    // --- Hillis-Steele over 4 chunks: 2 steps, wave-uniform branches ---
    #pragma unroll
    for (int s = 1; s < 4; s <<= 1) {
        float q0 = 0.f, q1 = 0.f, q2 = 0.f, q3 = 0.f;
        float g0 = 0.f, g1 = 0.f, g2 = 0.f, g3 = 0.f;
        if (c >= s) {
            q0 = cP[c - s][dg][s0 + 0]; q1 = cP[c - s][dg][s0 + 1];
            q2 = cP[c - s][dg][s0 + 2]; q3 = cP[c - s][dg][s0 + 3];
            g0 = cH[c - s][dg][s0 + 0]; g1 = cH[c - s][dg][s0 + 1];
            g2 = cH[c - s][dg][s0 + 2]; g3 = cH[c - s][dg][s0 + 3];
        }
        __syncthreads();
        if (c >= s) {
            h0 += p0 * g0; h1 += p1 * g1; h2 += p2 * g2; h3 += p3 * g3;
            p0 *= q0; p1 *= q1; p2 *= q2; p3 *= q3;
            cP[c][dg][s0 + 0] = p0; cP[c][dg][s0 + 1] = p1;
            cP[c][dg][s0 + 2] = p2; cP[c][dg][s0 + 3] = p3;
            cH[c][dg][s0 + 0] = h0; cH[c][dg][s0 + 1] = h1;
            cH[c][dg][s0 + 2] = h2; cH[c][dg][s0 + 3] = h3;
        }
        __syncthreads();
    }
    // entry state = inclusive prefix of chunk c-1
    h0 = h1 = h2 = h3 = 0.f;
    if (c > 0) {
        h0 = cH[c - 1][dg][s0 + 0]; h1 = cH[c - 1][dg][s0 + 1];
        h2 = cH[c - 1][dg][s0 + 2]; h3 = cH[c - 1][dg][s0 + 3];
    }
    // --- pass 2: rescan from true entry state, emit y ---
    const float dpar = Dp[d];
    for (int i = 0; i < 32; ++i) {
        const int t = t0 + i;
        float dtv = (float)dtp[t * 512];
        float uv  = bf2f(up[t * 512]);
        float du = dtv * uv;
        float e0 = __expf(dtv * A0), e1 = __expf(dtv * A1);
        float e2 = __expf(dtv * A2), e3 = __expf(dtv * A3);
        h0 = h0 * e0 + du * bc[t][s0 + 0];
        h1 = h1 * e1 + du * bc[t][s0 + 1];
        h2 = h2 * e2 + du * bc[t][s0 + 2];
        h3 = h3 * e3 + du * bc[t][s0 + 3];
        float y = h0 * bc[t][16 + s0 + 0] + h1 * bc[t][16 + s0 + 1]
                + h2 * bc[t][16 + s0 + 2] + h3 * bc[t][16 + s0 + 3];
        y += __shfl_xor(y, 1);
        y += __shfl_xor(y, 2);
        if (sub == 0) {
            float zv = bf2f(zp[t * 512]);
            float yf = (y + uv * dpar) * (zv / (1.f + __expf(-zv)));
            yp[t * 512] = f2bf(yf);
        }
    }
}

// ---------------------------------------------------------------------------
// out = LayerNorm( y_bf[16384 x 512] @ W_out_bf[256 x 512]^T ) with permuted store.
__global__ __launch_bounds__(256, 2) void k_out_ln(const unsigned short* __restrict__ Y,
                                                   const unsigned short* __restrict__ Wb,
                                                   const float* __restrict__ gamma,
                                                   const float* __restrict__ beta,
                                                   float* __restrict__ out) {
    __shared__ float s_sum[32], s_sq[32];
    const int w = threadIdx.x >> 6, l = threadIdx.x & 63;
    const int lr = l & 15, lg = l >> 4;
    const int row0 = blockIdx.x * 32;
    const int n0 = w * 64;
    f32x4 acc[2][4] = {};
    for (int k0 = 0; k0 < 512; k0 += 32) {
        const int ka = k0 + lg * 8;
        bf16x8 a[2], b[4];
        #pragma unroll
        for (int mi = 0; mi < 2; ++mi)
            a[mi] = *(const bf16x8*)(Y + (size_t)(row0 + mi * 16 + lr) * 512 + ka);
        #pragma unroll
        for (int ni = 0; ni < 4; ++ni)
            b[ni] = *(const bf16x8*)(Wb + (size_t)(n0 + ni * 16 + lr) * 512 + ka);
        #pragma unroll
        for (int mi = 0; mi < 2; ++mi)
            #pragma unroll
            for (int ni = 0; ni < 4; ++ni)
                acc[mi][ni] = __builtin_amdgcn_mfma_f32_16x16x32_bf16(a[mi], b[ni], acc[mi][ni], 0, 0, 0);
    }
    if (threadIdx.x < 32) { s_sum[threadIdx.x] = 0.f; s_sq[threadIdx.x] = 0.f; }
    __syncthreads();
    #pragma unroll
    for (int mi = 0; mi < 2; ++mi)
        #pragma unroll
        for (int r = 0; r < 4; ++r) {
            float s = 0.f, q = 0.f;
            #pragma unroll
            for (int ni = 0; ni < 4; ++ni) { float v = acc[mi][ni][r]; s += v; q += v * v; }
            #pragma unroll
            for (int m = 1; m < 16; m <<= 1) { s += __shfl_xor(s, m, 64); q += __shfl_xor(q, m, 64); }
            if (lr == 0) {
                atomicAdd(&s_sum[mi * 16 + lg * 4 + r], s);
                atomicAdd(&s_sq[mi * 16 + lg * 4 + r], q);
            }
        }
    __syncthreads();
    float g[4], be[4];
    #pragma unroll
    for (int ni = 0; ni < 4; ++ni) {
        g[ni] = gamma[n0 + ni * 16 + lr];
        be[ni] = beta[n0 + ni * 16 + lr];
    }
    #pragma unroll
    for (int mi = 0; mi < 2; ++mi)
        #pragma unroll
        for (int r = 0; r < 4; ++r) {
            const int rl = mi * 16 + lg * 4 + r;
            const int row = row0 + rl;
            const float mu = s_sum[rl] * (1.f / 256.f);
            const float var = s_sq[rl] * (1.f / 256.f) - mu * mu;
            const float rs = rsqrtf(var + 1e-5f);
            const int t = row & 127, bn = row >> 7;
            const int nn = bn & 63, bb = bn >> 6;
            float* orow = out + ((((size_t)(bb * 128 + t)) * 64 + nn) << 8);
            #pragma unroll
            for (int ni = 0; ni < 4; ++ni)
                orow[n0 + ni * 16 + lr] = (acc[mi][ni][r] - mu) * rs * g[ni] + be[ni];
        }
}

// ---------------------------------------------------------------------------
extern "C" void kernel_launch(void* const* d_in, const int* in_sizes, int n_in,
                              void* d_out, int out_size, void* d_ws, size_t ws_size,
                              hipStream_t stream) {
    const float* x      = (const float*)d_in[0];
    const float* W_in   = (const float*)d_in[1];
    const float* W_conv = (const float*)d_in[2];
    const float* b_conv = (const float*)d_in[3];
    const float* W_xprj = (const float*)d_in[4];
    const float* W_dt   = (const float*)d_in[5];
    const float* b_dt   = (const float*)d_in[6];
    const float* A_log  = (const float*)d_in[7];
    const float* D_par  = (const float*)d_in[8];
    const float* W_out  = (const float*)d_in[9];
    const float* gamma  = (const float*)d_in[10];
    const float* beta   = (const float*)d_in[11];
    float* out = (float*)d_out;

    char* ws = (char*)d_ws;
    size_t off = 0;
    auto alloc = [&](size_t bytes) -> void* {
        void* p = ws + off;
        off += (bytes + 255) & ~(size_t)255;
        return p;
    };
    // --- overlay region: dead after k_xproj; dtb aliases it ---
    unsigned short* Xbf   = (unsigned short*)alloc(16384ull * 256 * 2);  // 8.4 MB
    unsigned short* Winb  = (unsigned short*)alloc(1024ull * 256 * 2);
    unsigned short* Wxpb  = (unsigned short*)alloc(48ull * 512 * 2);
    unsigned short* xp    = (unsigned short*)alloc(16384ull * 512 * 2);  // 16.8 MB
    // --- live to the end ---
    unsigned short* Woutb = (unsigned short*)alloc(256ull * 512 * 2);
    unsigned short* zb    = (unsigned short*)alloc(16384ull * 512 * 2);
    unsigned short* ub    = (unsigned short*)alloc(16384ull * 512 * 2);
    float*          xdbl  = (float*)alloc(16384ull * 48 * 4);
    unsigned short* yb    = (unsigned short*)alloc(16384ull * 512 * 2);
    _Float16*       dtb   = (_Float16*)(ws);  // alias over Xbf..xp (dead by then)
    if (off > ws_size) return;

    k_prep_x<<<4096, 256, 0, stream>>>(x, (unsigned int*)Xbf);
    k_f2bf<<<256, 256, 0, stream>>>(W_in, (unsigned int*)Winb, 65536);
    k_f2bf<<<24, 256, 0, stream>>>(W_xprj, (unsigned int*)Wxpb, 6144);
    k_f2bf<<<128, 256, 0, stream>>>(W_out, (unsigned int*)Woutb, 32768);
    k_gemm1<<<dim3(64, 16), 256, 0, stream>>>(Xbf, Winb, xp, zb);
    k_conv<<<16384, 256, 0, stream>>>(xp, W_conv, b_conv, (unsigned int*)ub);
    k_xproj<<<256, 256, 0, stream>>>(ub, Wxpb, xdbl);
    k_dt<<<32768, 256, 0, stream>>>(xdbl, W_dt, b_dt, dtb);
    k_scan<<<2048, 512, 0, stream>>>(dtb, xdbl, ub, zb, A_log, D_par, yb);
    k_out_ln<<<512, 256, 0, stream>>>(yb, Woutb, gamma, beta, out);
}

// Round 5
// 233.456 us; speedup vs baseline: 1.7504x; 1.0388x over previous
//
#include <hip/hip_runtime.h>

typedef short bf16x8 __attribute__((ext_vector_type(8)));
typedef float f32x4 __attribute__((ext_vector_type(4)));

__device__ __forceinline__ unsigned short f2bf(float f) {
    unsigned int u = __builtin_bit_cast(unsigned int, f);
    u = (u + 0x7FFFu + ((u >> 16) & 1u)) >> 16;
    return (unsigned short)u;
}
__device__ __forceinline__ float bf2f(unsigned short h) {
    unsigned int u = ((unsigned int)h) << 16;
    return __builtin_bit_cast(float, u);
}

// ---------------------------------------------------------------------------
// Prep: permute x (B,T,N,Dm) -> Xbf rows r = bn*128+t, bn = b*64+n; fp32->bf16
__global__ __launch_bounds__(256) void k_prep_x(const float* __restrict__ x,
                                                unsigned int* __restrict__ Xbf2) {
    int tid = blockIdx.x * 256 + threadIdx.x;
    int c4 = tid & 63;      // group of 4 columns
    int r  = tid >> 6;      // output row
    int t = r & 127, bn = r >> 7;
    int n = bn & 63, b = bn >> 6;
    const float4 v = *((const float4*)(x + ((((size_t)(b * 128 + t)) * 64 + n) << 8)) + c4);
    uint2 o;
    o.x = (unsigned int)f2bf(v.x) | ((unsigned int)f2bf(v.y) << 16);
    o.y = (unsigned int)f2bf(v.z) | ((unsigned int)f2bf(v.w) << 16);
    *((uint2*)(Xbf2 + ((size_t)r << 7)) + c4) = o;
}

// Generic fp32 -> bf16 convert, 4 elements/thread (count % 4 == 0).
__global__ __launch_bounds__(256) void k_f2bf(const float* __restrict__ in,
                                              unsigned int* __restrict__ out, int n4) {
    int tid = blockIdx.x * 256 + threadIdx.x;
    if (tid >= n4) return;
    float4 v = ((const float4*)in)[tid];
    uint2 o;
    o.x = (unsigned int)f2bf(v.x) | ((unsigned int)f2bf(v.y) << 16);
    o.y = (unsigned int)f2bf(v.z) | ((unsigned int)f2bf(v.w) << 16);
    ((uint2*)out)[tid] = o;
}

// ---------------------------------------------------------------------------
// GEMM1: xz[16384 x 1024] = Xbf[16384 x 256] @ W_in_bf[1024 x 256]^T
__global__ __launch_bounds__(256, 2) void k_gemm1(const unsigned short* __restrict__ A,
                                                  const unsigned short* __restrict__ Bw,
                                                  unsigned short* __restrict__ xp,
                                                  unsigned short* __restrict__ z) {
    const int w = threadIdx.x >> 6, l = threadIdx.x & 63;
    const int lr = l & 15, lg = l >> 4;
    const int row0 = blockIdx.x * 256 + w * 64;
    const int n0 = blockIdx.y * 64;
    f32x4 acc[4][4] = {};
    for (int k0 = 0; k0 < 256; k0 += 32) {
        const int ka = k0 + lg * 8;
        bf16x8 a[4], b[4];
        #pragma unroll
        for (int mi = 0; mi < 4; ++mi)
            a[mi] = *(const bf16x8*)(A + (size_t)(row0 + mi * 16 + lr) * 256 + ka);
        #pragma unroll
        for (int ni = 0; ni < 4; ++ni)
            b[ni] = *(const bf16x8*)(Bw + (size_t)(n0 + ni * 16 + lr) * 256 + ka);
        #pragma unroll
        for (int mi = 0; mi < 4; ++mi)
            #pragma unroll
            for (int ni = 0; ni < 4; ++ni)
                acc[mi][ni] = __builtin_amdgcn_mfma_f32_16x16x32_bf16(a[mi], b[ni], acc[mi][ni], 0, 0, 0);
    }
    const bool isz = (n0 >= 512);
    unsigned short* dst = isz ? z : xp;
    const int c0 = isz ? (n0 - 512) : n0;
    #pragma unroll
    for (int mi = 0; mi < 4; ++mi)
        #pragma unroll
        for (int r = 0; r < 4; ++r) {
            const int row = row0 + mi * 16 + lg * 4 + r;
            #pragma unroll
            for (int ni = 0; ni < 4; ++ni)
                dst[(size_t)row * 512 + c0 + ni * 16 + lr] = f2bf(acc[mi][ni][r]);
        }
}

// ---------------------------------------------------------------------------
// Depthwise causal conv(4) + bias + SiLU, fully parallel over (bn, t, d-pair).
__global__ __launch_bounds__(256) void k_conv(const unsigned short* __restrict__ xp,
                                              const float* __restrict__ Wc,
                                              const float* __restrict__ bcv,
                                              unsigned int* __restrict__ ub2) {
    int tid = blockIdx.x * 256 + threadIdx.x;
    int d2 = tid & 255, r = tid >> 8;   // r = bn*128 + t
    int t = r & 127, bn = r >> 7;
    int d = d2 << 1;
    const unsigned short* src = xp + (size_t)bn * 65536 + d;
    f32x4 wa = *(const f32x4*)(Wc + d * 4);
    f32x4 wb = *(const f32x4*)(Wc + d * 4 + 4);
    float a0 = bcv[d], a1 = bcv[d + 1];
    #pragma unroll
    for (int k = 0; k < 4; ++k) {
        int tt = t - 3 + k;
        if (tt >= 0) {
            unsigned int p = *(const unsigned int*)(src + (size_t)tt * 512);
            a0 += bf2f((unsigned short)(p & 0xFFFFu)) * wa[k];
            a1 += bf2f((unsigned short)(p >> 16)) * wb[k];
        }
    }
    float u0 = a0 / (1.f + __expf(-a0));
    float u1 = a1 / (1.f + __expf(-a1));
    ub2[((size_t)bn * 65536 + (size_t)t * 512 + d) >> 1] =
        (unsigned int)f2bf(u0) | ((unsigned int)f2bf(u1) << 16);
}

// ---------------------------------------------------------------------------
// x_dbl[16384 x 48] = u_bf[16384 x 512] @ W_xproj_bf[48 x 512]^T  (fp32 out)
__global__ __launch_bounds__(256, 2) void k_xproj(const unsigned short* __restrict__ U,
                                                  const unsigned short* __restrict__ Wb,
                                                  float* __restrict__ xdbl) {
    const int w = threadIdx.x >> 6, l = threadIdx.x & 63;
    const int lr = l & 15, lg = l >> 4;
    const int row0 = blockIdx.x * 64 + w * 16;
    f32x4 acc[3] = {};
    for (int k0 = 0; k0 < 512; k0 += 32) {
        const int ka = k0 + lg * 8;
        bf16x8 a = *(const bf16x8*)(U + (size_t)(row0 + lr) * 512 + ka);
        bf16x8 b[3];
        #pragma unroll
        for (int ni = 0; ni < 3; ++ni)
            b[ni] = *(const bf16x8*)(Wb + (size_t)(ni * 16 + lr) * 512 + ka);
        #pragma unroll
        for (int ni = 0; ni < 3; ++ni)
            acc[ni] = __builtin_amdgcn_mfma_f32_16x16x32_bf16(a, b[ni], acc[ni], 0, 0, 0);
    }
    #pragma unroll
    for (int r = 0; r < 4; ++r) {
        const int row = row0 + lg * 4 + r;
        #pragma unroll
        for (int ni = 0; ni < 3; ++ni)
            xdbl[(size_t)row * 48 + ni * 16 + lr] = acc[ni][r];
    }
}

// ---------------------------------------------------------------------------
// dt = softplus(dt_raw @ W_dt^T + b_dt), fully parallel. One thread per (r, d).
__global__ __launch_bounds__(256) void k_dt(const float* __restrict__ xdbl,
                                            const float* __restrict__ W_dt,
                                            const float* __restrict__ b_dt,
                                            _Float16* __restrict__ dtb) {
    int tid = blockIdx.x * 256 + threadIdx.x;
    int d = tid & 511, r = tid >> 9;
    const f32x4* xr = (const f32x4*)(xdbl + (size_t)r * 48);
    const f32x4* wd = (const f32x4*)(W_dt + d * 16);
    float dl = b_dt[d];
    #pragma unroll
    for (int k = 0; k < 4; ++k) {
        f32x4 xv = xr[k], wv = wd[k];
        dl += xv[0] * wv[0] + xv[1] * wv[1] + xv[2] * wv[2] + xv[3] * wv[3];
    }
    float dt = (dl > 20.f) ? dl : log1pf(__expf(dl));
    dtb[(size_t)r * 512 + d] = (_Float16)dt;
}

// ---------------------------------------------------------------------------
// Chunked parallel selective scan v3: exp-chain fast path.
// Block = 512 threads = 4 chunks(T=32) x 32 d x 4 state-lanes; grid 2048.
// A_log is tiled log(1..16) in this model => A[s] = -(s+1) =>
// dA_s = exp(-dt)^(s+1): ONE exp + ~7 full-rate muls per lane per step,
// replacing 4 transcendentals (R4 was exp-pipe-bound at ~98us).
// Runtime-verified per thread (tol 1e-3 rel); generic 4-exp fallback keeps
// correctness data-independent. Chunk product P via S = prod(E): P_j = S^(s+1).
__global__ __launch_bounds__(512, 8) void k_scan(const _Float16* __restrict__ dtb,
                                                 const float* __restrict__ xdbl,
                                                 const unsigned short* __restrict__ ub,
                                                 const unsigned short* __restrict__ zb,
                                                 const float* __restrict__ A_log,
                                                 const float* __restrict__ Dp,
                                                 unsigned short* __restrict__ yb) {
    __shared__ float bc[128][32];     // [t][ B(0..15) | C(16..31) ]
    __shared__ float cP[4][32][16];   // [chunk][dg][state]
    __shared__ float cH[4][32][16];
    const int bn = blockIdx.x >> 4;
    const int d0 = (blockIdx.x & 15) * 32;
    {   // stage B,C for this bn: 128 rows x 8 f32x4, 512 threads x 2 rounds
        const float* src = xdbl + (size_t)(bn * 128) * 48 + 16;
        #pragma unroll
        for (int k = 0; k < 2; ++k) {
            int li = threadIdx.x + k * 512;
            int row = li >> 3, c4 = li & 7;
            *(f32x4*)(&bc[row][c4 * 4]) = *(const f32x4*)(src + row * 48 + c4 * 4);
        }
    }
    const int sub = threadIdx.x & 3;          // state quad
    const int dg  = (threadIdx.x >> 2) & 31;  // d within group
    const int c   = threadIdx.x >> 7;         // chunk (wave-uniform: wave>>1)
    const int d   = d0 + dg;
    const int s0  = sub * 4;
    float A0, A1, A2, A3;
    {
        f32x4 al = *(const f32x4*)(A_log + d * 16 + s0);
        A0 = -__expf(al[0]); A1 = -__expf(al[1]);
        A2 = -__expf(al[2]); A3 = -__expf(al[3]);
    }
    // fast path valid iff A_j == -(s0+j+1) (to __expf approx tolerance)
    const bool fast = (fabsf(A0 + (float)(s0 + 1)) < 1e-3f * (s0 + 1)) &&
                      (fabsf(A1 + (float)(s0 + 2)) < 1e-3f * (s0 + 2)) &&
                      (fabsf(A2 + (float)(s0 + 3)) < 1e-3f * (s0 + 3)) &&
                      (fabsf(A3 + (float)(s0 + 4)) < 1e-3f * (s0 + 4));
    const int m1 = sub & 1, m2 = sub & 2;
    const _Float16* dtp = dtb + (size_t)(bn * 128) * 512 + d;
    const unsigned short* up = ub + (size_t)bn * 65536 + d;
    const unsigned short* zp = zb + (size_t)bn * 65536 + d;
    unsigned short* yp = yb + (size_t)bn * 65536 + d;
    const int t0 = c * 32;
    __syncthreads();
    // --- pass 1: local scan (h0=0), track chunk product ---
    float p0 = 1.f, p1 = 1.f, p2 = 1.f, p3 = 1.f;
    float h0 = 0.f, h1 = 0.f, h2 = 0.f, h3 = 0.f;
    if (fast) {
        float S = 1.f;
        for (int i = 0; i < 32; ++i) {
            const int t = t0 + i;
            float dtv = (float)dtp[t * 512];
            float du = dtv * bf2f(up[t * 512]);
            float E = __expf(-dtv);
            float E2 = E * E, E4 = E2 * E2, E8 = E4 * E4;
            float base = E * (m1 ? E4 : 1.f) * (m2 ? E8 : 1.f);  // E^(s0+1)
            float e1 = base * E, e2 = e1 * E, e3 = e2 * E;
            f32x4 Bv = *(const f32x4*)(&bc[t][s0]);
            h0 = h0 * base + du * Bv[0];
            h1 = h1 * e1 + du * Bv[1];
            h2 = h2 * e2 + du * Bv[2];
            h3 = h3 * e3 + du * Bv[3];
            S *= E;
        }
        float S2 = S * S, S4 = S2 * S2, S8 = S4 * S4;
        p0 = S * (m1 ? S4 : 1.f) * (m2 ? S8 : 1.f);
        p1 = p0 * S; p2 = p1 * S; p3 = p2 * S;
    } else {
        for (int i = 0; i < 32; ++i) {
            const int t = t0 + i;
            float dtv = (float)dtp[t * 512];
            float du = dtv * bf2f(up[t * 512]);
            float e0 = __expf(dtv * A0), e1 = __expf(dtv * A1);
            float e2 = __expf(dtv * A2), e3 = __expf(dtv * A3);
            f32x4 Bv = *(const f32x4*)(&bc[t][s0]);
            h0 = h0 * e0 + du * Bv[0]; p0 *= e0;
            h1 = h1 * e1 + du * Bv[1]; p1 *= e1;
            h2 = h2 * e2 + du * Bv[2]; p2 *= e2;
            h3 = h3 * e3 + du * Bv[3]; p3 *= e3;
        }
    }
    cP[c][dg][s0 + 0] = p0; cP[c][dg][s0 + 1] = p1;
    cP[c][dg][s0 + 2] = p2; cP[c][dg][s0 + 3] = p3;
    cH[c][dg][s0 + 0] = h0; cH[c][dg][s0 + 1] = h1;
    cH[c][dg][s0 + 2] = h2; cH[c][dg][s0 + 3] = h3;
    __syncthreads();
    // --- Hillis-Steele over 4 chunks: 2 steps, wave-uniform branches ---
    #pragma unroll
    for (int s = 1; s < 4; s <<= 1) {
        float q0 = 0.f, q1 = 0.f, q2 = 0.f, q3 = 0.f;
        float g0 = 0.f, g1 = 0.f, g2 = 0.f, g3 = 0.f;
        if (c >= s) {
            q0 = cP[c - s][dg][s0 + 0]; q1 = cP[c - s][dg][s0 + 1];
            q2 = cP[c - s][dg][s0 + 2]; q3 = cP[c - s][dg][s0 + 3];
            g0 = cH[c - s][dg][s0 + 0]; g1 = cH[c - s][dg][s0 + 1];
            g2 = cH[c - s][dg][s0 + 2]; g3 = cH[c - s][dg][s0 + 3];
        }
        __syncthreads();
        if (c >= s) {
            h0 += p0 * g0; h1 += p1 * g1; h2 += p2 * g2; h3 += p3 * g3;
            p0 *= q0; p1 *= q1; p2 *= q2; p3 *= q3;
            cP[c][dg][s0 + 0] = p0; cP[c][dg][s0 + 1] = p1;
            cP[c][dg][s0 + 2] = p2; cP[c][dg][s0 + 3] = p3;
            cH[c][dg][s0 + 0] = h0; cH[c][dg][s0 + 1] = h1;
            cH[c][dg][s0 + 2] = h2; cH[c][dg][s0 + 3] = h3;
        }
        __syncthreads();
    }
    // entry state = inclusive prefix of chunk c-1
    h0 = h1 = h2 = h3 = 0.f;
    if (c > 0) {
        h0 = cH[c - 1][dg][s0 + 0]; h1 = cH[c - 1][dg][s0 + 1];
        h2 = cH[c - 1][dg][s0 + 2]; h3 = cH[c - 1][dg][s0 + 3];
    }
    // --- pass 2: rescan from true entry state, emit y ---
    const float dpar = Dp[d];
    if (fast) {
        for (int i = 0; i < 32; ++i) {
            const int t = t0 + i;
            float dtv = (float)dtp[t * 512];
            float uv  = bf2f(up[t * 512]);
            float du = dtv * uv;
            float E = __expf(-dtv);
            float E2 = E * E, E4 = E2 * E2, E8 = E4 * E4;
            float base = E * (m1 ? E4 : 1.f) * (m2 ? E8 : 1.f);
            float e1 = base * E, e2 = e1 * E, e3 = e2 * E;
            f32x4 Bv = *(const f32x4*)(&bc[t][s0]);
            f32x4 Cv = *(const f32x4*)(&bc[t][16 + s0]);
            h0 = h0 * base + du * Bv[0];
            h1 = h1 * e1 + du * Bv[1];
            h2 = h2 * e2 + du * Bv[2];
            h3 = h3 * e3 + du * Bv[3];
            float y = h0 * Cv[0] + h1 * Cv[1] + h2 * Cv[2] + h3 * Cv[3];
            y += __shfl_xor(y, 1);
            y += __shfl_xor(y, 2);
            if (sub == 0) {
                float zv = bf2f(zp[t * 512]);
                float yf = (y + uv * dpar) * (zv / (1.f + __expf(-zv)));
                yp[t * 512] = f2bf(yf);
            }
        }
    } else {
        for (int i = 0; i < 32; ++i) {
            const int t = t0 + i;
            float dtv = (float)dtp[t * 512];
            float uv  = bf2f(up[t * 512]);
            float du = dtv * uv;
            float e0 = __expf(dtv * A0), e1 = __expf(dtv * A1);
            float e2 = __expf(dtv * A2), e3 = __expf(dtv * A3);
            f32x4 Bv = *(const f32x4*)(&bc[t][s0]);
            f32x4 Cv = *(const f32x4*)(&bc[t][16 + s0]);
            h0 = h0 * e0 + du * Bv[0];
            h1 = h1 * e1 + du * Bv[1];
            h2 = h2 * e2 + du * Bv[2];
            h3 = h3 * e3 + du * Bv[3];
            float y = h0 * Cv[0] + h1 * Cv[1] + h2 * Cv[2] + h3 * Cv[3];
            y += __shfl_xor(y, 1);
            y += __shfl_xor(y, 2);
            if (sub == 0) {
                float zv = bf2f(zp[t * 512]);
                float yf = (y + uv * dpar) * (zv / (1.f + __expf(-zv)));
                yp[t * 512] = f2bf(yf);
            }
        }
    }
}

// ---------------------------------------------------------------------------
// out = LayerNorm( y_bf[16384 x 512] @ W_out_bf[256 x 512]^T ) with permuted store.
__global__ __launch_bounds__(256, 2) void k_out_ln(const unsigned short* __restrict__ Y,
                                                   const unsigned short* __restrict__ Wb,
                                                   const float* __restrict__ gamma,
                                                   const float* __restrict__ beta,
                                                   float* __restrict__ out) {
    __shared__ float s_sum[32], s_sq[32];
    const int w = threadIdx.x >> 6, l = threadIdx.x & 63;
    const int lr = l & 15, lg = l >> 4;
    const int row0 = blockIdx.x * 32;
    const int n0 = w * 64;
    f32x4 acc[2][4] = {};
    for (int k0 = 0; k0 < 512; k0 += 32) {
        const int ka = k0 + lg * 8;
        bf16x8 a[2], b[4];
        #pragma unroll
        for (int mi = 0; mi < 2; ++mi)
            a[mi] = *(const bf16x8*)(Y + (size_t)(row0 + mi * 16 + lr) * 512 + ka);
        #pragma unroll
        for (int ni = 0; ni < 4; ++ni)
            b[ni] = *(const bf16x8*)(Wb + (size_t)(n0 + ni * 16 + lr) * 512 + ka);
        #pragma unroll
        for (int mi = 0; mi < 2; ++mi)
            #pragma unroll
            for (int ni = 0; ni < 4; ++ni)
                acc[mi][ni] = __builtin_amdgcn_mfma_f32_16x16x32_bf16(a[mi], b[ni], acc[mi][ni], 0, 0, 0);
    }
    if (threadIdx.x < 32) { s_sum[threadIdx.x] = 0.f; s_sq[threadIdx.x] = 0.f; }
    __syncthreads();
    #pragma unroll
    for (int mi = 0; mi < 2; ++mi)
        #pragma unroll
        for (int r = 0; r < 4; ++r) {
            float s = 0.f, q = 0.f;
            #pragma unroll
            for (int ni = 0; ni < 4; ++ni) { float v = acc[mi][ni][r]; s += v; q += v * v; }
            #pragma unroll
            for (int m = 1; m < 16; m <<= 1) { s += __shfl_xor(s, m, 64); q += __shfl_xor(q, m, 64); }
            if (lr == 0) {
                atomicAdd(&s_sum[mi * 16 + lg * 4 + r], s);
                atomicAdd(&s_sq[mi * 16 + lg * 4 + r], q);
            }
        }
    __syncthreads();
    float g[4], be[4];
    #pragma unroll
    for (int ni = 0; ni < 4; ++ni) {
        g[ni] = gamma[n0 + ni * 16 + lr];
        be[ni] = beta[n0 + ni * 16 + lr];
    }
    #pragma unroll
    for (int mi = 0; mi < 2; ++mi)
        #pragma unroll
        for (int r = 0; r < 4; ++r) {
            const int rl = mi * 16 + lg * 4 + r;
            const int row = row0 + rl;
            const float mu = s_sum[rl] * (1.f / 256.f);
            const float var = s_sq[rl] * (1.f / 256.f) - mu * mu;
            const float rs = rsqrtf(var + 1e-5f);
            const int t = row & 127, bn = row >> 7;
            const int nn = bn & 63, bb = bn >> 6;
            float* orow = out + ((((size_t)(bb * 128 + t)) * 64 + nn) << 8);
            #pragma unroll
            for (int ni = 0; ni < 4; ++ni)
                orow[n0 + ni * 16 + lr] = (acc[mi][ni][r] - mu) * rs * g[ni] + be[ni];
        }
}

// ---------------------------------------------------------------------------
extern "C" void kernel_launch(void* const* d_in, const int* in_sizes, int n_in,
                              void* d_out, int out_size, void* d_ws, size_t ws_size,
                              hipStream_t stream) {
    const float* x      = (const float*)d_in[0];
    const float* W_in   = (const float*)d_in[1];
    const float* W_conv = (const float*)d_in[2];
    const float* b_conv = (const float*)d_in[3];
    const float* W_xprj = (const float*)d_in[4];
    const float* W_dt   = (const float*)d_in[5];
    const float* b_dt   = (const float*)d_in[6];
    const float* A_log  = (const float*)d_in[7];
    const float* D_par  = (const float*)d_in[8];
    const float* W_out  = (const float*)d_in[9];
    const float* gamma  = (const float*)d_in[10];
    const float* beta   = (const float*)d_in[11];
    float* out = (float*)d_out;

    char* ws = (char*)d_ws;
    size_t off = 0;
    auto alloc = [&](size_t bytes) -> void* {
        void* p = ws + off;
        off += (bytes + 255) & ~(size_t)255;
        return p;
    };
    // --- overlay region: dead after k_xproj; dtb aliases it ---
    unsigned short* Xbf   = (unsigned short*)alloc(16384ull * 256 * 2);  // 8.4 MB
    unsigned short* Winb  = (unsigned short*)alloc(1024ull * 256 * 2);
    unsigned short* Wxpb  = (unsigned short*)alloc(48ull * 512 * 2);
    unsigned short* xp    = (unsigned short*)alloc(16384ull * 512 * 2);  // 16.8 MB
    // --- live to the end ---
    unsigned short* Woutb = (unsigned short*)alloc(256ull * 512 * 2);
    unsigned short* zb    = (unsigned short*)alloc(16384ull * 512 * 2);
    unsigned short* ub    = (unsigned short*)alloc(16384ull * 512 * 2);
    float*          xdbl  = (float*)alloc(16384ull * 48 * 4);
    unsigned short* yb    = (unsigned short*)alloc(16384ull * 512 * 2);
    _Float16*       dtb   = (_Float16*)(ws);  // alias over Xbf..xp (dead by then)
    if (off > ws_size) return;

    k_prep_x<<<4096, 256, 0, stream>>>(x, (unsigned int*)Xbf);
    k_f2bf<<<256, 256, 0, stream>>>(W_in, (unsigned int*)Winb, 65536);
    k_f2bf<<<24, 256, 0, stream>>>(W_xprj, (unsigned int*)Wxpb, 6144);
    k_f2bf<<<128, 256, 0, stream>>>(W_out, (unsigned int*)Woutb, 32768);
    k_gemm1<<<dim3(64, 16), 256, 0, stream>>>(Xbf, Winb, xp, zb);
    k_conv<<<16384, 256, 0, stream>>>(xp, W_conv, b_conv, (unsigned int*)ub);
    k_xproj<<<256, 256, 0, stream>>>(ub, Wxpb, xdbl);
    k_dt<<<32768, 256, 0, stream>>>(xdbl, W_dt, b_dt, dtb);
    k_scan<<<2048, 512, 0, stream>>>(dtb, xdbl, ub, zb, A_log, D_par, yb);
    k_out_ln<<<512, 256, 0, stream>>>(yb, Woutb, gamma, beta, out);
}

// Round 6
// 191.636 us; speedup vs baseline: 2.1324x; 1.2182x over previous
//
#include <hip/hip_runtime.h>

typedef short bf16x8 __attribute__((ext_vector_type(8)));
typedef float f32x4 __attribute__((ext_vector_type(4)));

__device__ __forceinline__ unsigned short f2bf(float f) {
    unsigned int u = __builtin_bit_cast(unsigned int, f);
    u = (u + 0x7FFFu + ((u >> 16) & 1u)) >> 16;
    return (unsigned short)u;
}
__device__ __forceinline__ float bf2f(unsigned short h) {
    unsigned int u = ((unsigned int)h) << 16;
    return __builtin_bit_cast(float, u);
}

// ---------------------------------------------------------------------------
// Prep: permute x (B,T,N,Dm) -> Xbf rows r = bn*128+t, bn = b*64+n; fp32->bf16
__global__ __launch_bounds__(256) void k_prep_x(const float* __restrict__ x,
                                                unsigned int* __restrict__ Xbf2) {
    int tid = blockIdx.x * 256 + threadIdx.x;
    int c4 = tid & 63;
    int r  = tid >> 6;
    int t = r & 127, bn = r >> 7;
    int n = bn & 63, b = bn >> 6;
    const float4 v = *((const float4*)(x + ((((size_t)(b * 128 + t)) * 64 + n) << 8)) + c4);
    uint2 o;
    o.x = (unsigned int)f2bf(v.x) | ((unsigned int)f2bf(v.y) << 16);
    o.y = (unsigned int)f2bf(v.z) | ((unsigned int)f2bf(v.w) << 16);
    *((uint2*)(Xbf2 + ((size_t)r << 7)) + c4) = o;
}

// Generic fp32 -> bf16 convert, 4 elements/thread (count % 4 == 0).
__global__ __launch_bounds__(256) void k_f2bf(const float* __restrict__ in,
                                              unsigned int* __restrict__ out, int n4) {
    int tid = blockIdx.x * 256 + threadIdx.x;
    if (tid >= n4) return;
    float4 v = ((const float4*)in)[tid];
    uint2 o;
    o.x = (unsigned int)f2bf(v.x) | ((unsigned int)f2bf(v.y) << 16);
    o.y = (unsigned int)f2bf(v.z) | ((unsigned int)f2bf(v.w) << 16);
    ((uint2*)out)[tid] = o;
}

// ---------------------------------------------------------------------------
// GEMM1 v2: xz[16384 x 1024] = Xbf[16384 x 256] @ W_in_bf[1024 x 256]^T
// 128x128 tile, BK=64, double-buffered LDS, reg-staged (T14 split: load early,
// ds_write after compute), XOR-swizzle (row&7)*8 elems on BOTH store and read
// (frag ds_read_b128 becomes uniform-8-slot = optimal; unswizzled is 16-way).
__global__ __launch_bounds__(256, 2) void k_gemm1(const unsigned short* __restrict__ A,
                                                  const unsigned short* __restrict__ Bw,
                                                  unsigned short* __restrict__ xp,
                                                  unsigned short* __restrict__ z) {
    __shared__ unsigned short As[2][128][64];
    __shared__ unsigned short Bs[2][128][64];
    const int tid = threadIdx.x;
    const int l = tid & 63, w = tid >> 6;
    const int lr = l & 15, lg = l >> 4;
    const int wr = w >> 1, wc = w & 1;
    const int row0 = blockIdx.x * 128;
    const int n0b  = blockIdx.y * 128;

    bf16x8 sa[4], sb[4];
    auto LOAD = [&](int k0) {
        #pragma unroll
        for (int r2 = 0; r2 < 4; ++r2) {
            int cc = tid + r2 * 256;
            int row = cc >> 3, ke = (cc & 7) * 8;
            sa[r2] = *(const bf16x8*)(A  + (size_t)(row0 + row) * 256 + k0 + ke);
            sb[r2] = *(const bf16x8*)(Bw + (size_t)(n0b + row) * 256 + k0 + ke);
        }
    };
    auto WRITE = [&](int buf) {
        #pragma unroll
        for (int r2 = 0; r2 < 4; ++r2) {
            int cc = tid + r2 * 256;
            int row = cc >> 3, ke = (cc & 7) * 8;
            int ks = ke ^ ((row & 7) * 8);
            *(bf16x8*)&As[buf][row][ks] = sa[r2];
            *(bf16x8*)&Bs[buf][row][ks] = sb[r2];
        }
    };

    f32x4 acc[4][4] = {};
    LOAD(0); WRITE(0);
    __syncthreads();
    int cur = 0;
    for (int kt = 0; kt < 4; ++kt) {
        if (kt < 3) LOAD((kt + 1) * 64);
        #pragma unroll
        for (int ks = 0; ks < 2; ++ks) {
            const int ka = ks * 32;
            bf16x8 a[4], b[4];
            #pragma unroll
            for (int mi = 0; mi < 4; ++mi) {
                int row = wr * 64 + mi * 16 + lr;
                int e = (ka + lg * 8) ^ ((row & 7) * 8);
                a[mi] = *(const bf16x8*)&As[cur][row][e];
            }
            #pragma unroll
            for (int ni = 0; ni < 4; ++ni) {
                int row = wc * 64 + ni * 16 + lr;
                int e = (ka + lg * 8) ^ ((row & 7) * 8);
                b[ni] = *(const bf16x8*)&Bs[cur][row][e];
            }
            #pragma unroll
            for (int mi = 0; mi < 4; ++mi)
                #pragma unroll
                for (int ni = 0; ni < 4; ++ni)
                    acc[mi][ni] = __builtin_amdgcn_mfma_f32_16x16x32_bf16(a[mi], b[ni], acc[mi][ni], 0, 0, 0);
        }
        if (kt < 3) WRITE(cur ^ 1);
        __syncthreads();
        cur ^= 1;
    }
    const bool isz = (blockIdx.y >= 4);
    unsigned short* dst = isz ? z : xp;
    const int colbase = (blockIdx.y - (isz ? 4 : 0)) * 128 + wc * 64;
    #pragma unroll
    for (int mi = 0; mi < 4; ++mi)
        #pragma unroll
        for (int r = 0; r < 4; ++r) {
            const int row = row0 + wr * 64 + mi * 16 + lg * 4 + r;
            #pragma unroll
            for (int ni = 0; ni < 4; ++ni)
                dst[(size_t)row * 512 + colbase + ni * 16 + lr] = f2bf(acc[mi][ni][r]);
        }
}

// ---------------------------------------------------------------------------
// Depthwise causal conv(4) + bias + SiLU, fully parallel over (bn, t, d-pair).
__global__ __launch_bounds__(256) void k_conv(const unsigned short* __restrict__ xp,
                                              const float* __restrict__ Wc,
                                              const float* __restrict__ bcv,
                                              unsigned int* __restrict__ ub2) {
    int tid = blockIdx.x * 256 + threadIdx.x;
    int d2 = tid & 255, r = tid >> 8;
    int t = r & 127, bn = r >> 7;
    int d = d2 << 1;
    const unsigned short* src = xp + (size_t)bn * 65536 + d;
    f32x4 wa = *(const f32x4*)(Wc + d * 4);
    f32x4 wb = *(const f32x4*)(Wc + d * 4 + 4);
    float a0 = bcv[d], a1 = bcv[d + 1];
    #pragma unroll
    for (int k = 0; k < 4; ++k) {
        int tt = t - 3 + k;
        if (tt >= 0) {
            unsigned int p = *(const unsigned int*)(src + (size_t)tt * 512);
            a0 += bf2f((unsigned short)(p & 0xFFFFu)) * wa[k];
            a1 += bf2f((unsigned short)(p >> 16)) * wb[k];
        }
    }
    float u0 = a0 / (1.f + __expf(-a0));
    float u1 = a1 / (1.f + __expf(-a1));
    ub2[((size_t)bn * 65536 + (size_t)t * 512 + d) >> 1] =
        (unsigned int)f2bf(u0) | ((unsigned int)f2bf(u1) << 16);
}

// ---------------------------------------------------------------------------
// x_dbl[16384 x 48] = u_bf[16384 x 512] @ W_xproj_bf[48 x 512]^T  (fp32 out)
__global__ __launch_bounds__(256, 2) void k_xproj(const unsigned short* __restrict__ U,
                                                  const unsigned short* __restrict__ Wb,
                                                  float* __restrict__ xdbl) {
    const int w = threadIdx.x >> 6, l = threadIdx.x & 63;
    const int lr = l & 15, lg = l >> 4;
    const int row0 = blockIdx.x * 64 + w * 16;
    f32x4 acc[3] = {};
    for (int k0 = 0; k0 < 512; k0 += 32) {
        const int ka = k0 + lg * 8;
        bf16x8 a = *(const bf16x8*)(U + (size_t)(row0 + lr) * 512 + ka);
        bf16x8 b[3];
        #pragma unroll
        for (int ni = 0; ni < 3; ++ni)
            b[ni] = *(const bf16x8*)(Wb + (size_t)(ni * 16 + lr) * 512 + ka);
        #pragma unroll
        for (int ni = 0; ni < 3; ++ni)
            acc[ni] = __builtin_amdgcn_mfma_f32_16x16x32_bf16(a, b[ni], acc[ni], 0, 0, 0);
    }
    #pragma unroll
    for (int r = 0; r < 4; ++r) {
        const int row = row0 + lg * 4 + r;
        #pragma unroll
        for (int ni = 0; ni < 3; ++ni)
            xdbl[(size_t)row * 48 + ni * 16 + lr] = acc[ni][r];
    }
}

// ---------------------------------------------------------------------------
// dt = softplus(dt_raw @ W_dt^T + b_dt), fully parallel. One thread per (r, d).
__global__ __launch_bounds__(256) void k_dt(const float* __restrict__ xdbl,
                                            const float* __restrict__ W_dt,
                                            const float* __restrict__ b_dt,
                                            _Float16* __restrict__ dtb) {
    int tid = blockIdx.x * 256 + threadIdx.x;
    int d = tid & 511, r = tid >> 9;
    const f32x4* xr = (const f32x4*)(xdbl + (size_t)r * 48);
    const f32x4* wd = (const f32x4*)(W_dt + d * 16);
    float dl = b_dt[d];
    #pragma unroll
    for (int k = 0; k < 4; ++k) {
        f32x4 xv = xr[k], wv = wd[k];
        dl += xv[0] * wv[0] + xv[1] * wv[1] + xv[2] * wv[2] + xv[3] * wv[3];
    }
    float dt = (dl > 20.f) ? dl : log1pf(__expf(dl));
    dtb[(size_t)r * 512 + d] = (_Float16)dt;
}

// ---------------------------------------------------------------------------
// Chunked parallel selective scan v4: 16 states per lane (layout B).
// Block = 256 thr = 4 chunks(T=32) x 64 d (wave = one chunk, d coalesced).
// Grid = 128 bn x 8 dgroups = 1024 blocks. LDS 48 KB -> 3 blocks/CU.
// Removes the 4x duplication of dt/u/z loads + exp + power-chain of the
// 4-lane layout, and the per-step shuffles (y-dot is lane-local).
// Fast path: A_j = -(j+1) (A_log = log(1..16)) => decays E^(j+1) from one
// E=exp(-dt) via 4 mul-chains; chunk product P_j = S^(j+1), S = prod E.
// Generic fallback (in-loop A_log loads + exps) keeps data-independence.
__global__ __launch_bounds__(256, 3) void k_scan(const _Float16* __restrict__ dtb,
                                                 const float* __restrict__ xdbl,
                                                 const unsigned short* __restrict__ ub,
                                                 const unsigned short* __restrict__ zb,
                                                 const float* __restrict__ A_log,
                                                 const float* __restrict__ Dp,
                                                 unsigned short* __restrict__ yb) {
    __shared__ float bc[128][32];     // [t][ B(0..15) | C(16..31) ]
    __shared__ float cP[4][64][16];   // [chunk][dg][state]
    __shared__ float cH[4][64][16];
    const int bn = blockIdx.x >> 3;
    const int d0 = (blockIdx.x & 7) * 64;
    {   // stage B,C for this bn
        const float* src = xdbl + (size_t)(bn * 128) * 48 + 16;
        #pragma unroll
        for (int k = 0; k < 4; ++k) {
            int li = threadIdx.x + k * 256;
            int row = li >> 3, c4 = li & 7;
            *(f32x4*)(&bc[row][c4 * 4]) = *(const f32x4*)(src + row * 48 + c4 * 4);
        }
    }
    const int dg = threadIdx.x & 63;
    const int c  = threadIdx.x >> 6;   // chunk == wave id
    const int d  = d0 + dg;
    // structured-A check (one-time, 16 exps)
    bool fast = true;
    #pragma unroll
    for (int j = 0; j < 16; ++j) {
        float aj = __expf(A_log[d * 16 + j]);
        fast = fast && (fabsf(aj - (float)(j + 1)) < 1e-3f * (float)(j + 1));
    }
    const _Float16* dtp = dtb + (size_t)(bn * 128) * 512 + d;
    const unsigned short* up = ub + (size_t)bn * 65536 + d;
    const unsigned short* zp = zb + (size_t)bn * 65536 + d;
    unsigned short* yp = yb + (size_t)bn * 65536 + d;
    const int t0 = c * 32;
    float h[16], p[16];
    #pragma unroll
    for (int j = 0; j < 16; ++j) h[j] = 0.f;
    __syncthreads();
    // --- pass 1: local scan (h0=0), track per-state chunk product ---
    if (fast) {
        float S = 1.f;
        for (int i = 0; i < 32; ++i) {
            const int t = t0 + i;
            float dtv = (float)dtp[t * 512];
            float du  = dtv * bf2f(up[t * 512]);
            float E = __expf(-dtv);
            float E2 = E * E, E4 = E2 * E2, E8 = E4 * E4;
            float b1 = E4 * E, b2 = E8 * E, b3 = b2 * E4;
            S *= E;
            f32x4 B0 = *(const f32x4*)&bc[t][0];
            f32x4 B1 = *(const f32x4*)&bc[t][4];
            f32x4 B2 = *(const f32x4*)&bc[t][8];
            f32x4 B3 = *(const f32x4*)&bc[t][12];
            float e;
            e = E;  h[0] = h[0]*e + du*B0[0];  e *= E; h[1] = h[1]*e + du*B0[1];
            e *= E; h[2] = h[2]*e + du*B0[2];  e *= E; h[3] = h[3]*e + du*B0[3];
            e = b1; h[4] = h[4]*e + du*B1[0];  e *= E; h[5] = h[5]*e + du*B1[1];
            e *= E; h[6] = h[6]*e + du*B1[2];  e *= E; h[7] = h[7]*e + du*B1[3];
            e = b2; h[8] = h[8]*e + du*B2[0];  e *= E; h[9] = h[9]*e + du*B2[1];
            e *= E; h[10] = h[10]*e + du*B2[2]; e *= E; h[11] = h[11]*e + du*B2[3];
            e = b3; h[12] = h[12]*e + du*B3[0]; e *= E; h[13] = h[13]*e + du*B3[1];
            e *= E; h[14] = h[14]*e + du*B3[2]; e *= E; h[15] = h[15]*e + du*B3[3];
        }
        float S2 = S * S, S4 = S2 * S2, S8 = S4 * S4;
        float c1 = S4 * S, c2 = S8 * S, c3 = c2 * S4;
        float e;
        e = S;  p[0] = e;  e *= S; p[1] = e;  e *= S; p[2] = e;  e *= S; p[3] = e;
        e = c1; p[4] = e;  e *= S; p[5] = e;  e *= S; p[6] = e;  e *= S; p[7] = e;
        e = c2; p[8] = e;  e *= S; p[9] = e;  e *= S; p[10] = e; e *= S; p[11] = e;
        e = c3; p[12] = e; e *= S; p[13] = e; e *= S; p[14] = e; e *= S; p[15] = e;
    } else {
        #pragma unroll
        for (int j = 0; j < 16; ++j) p[j] = 1.f;
        for (int i = 0; i < 32; ++i) {
            const int t = t0 + i;
            float dtv = (float)dtp[t * 512];
            float du  = dtv * bf2f(up[t * 512]);
            #pragma unroll
            for (int j = 0; j < 16; ++j) {
                float e = __expf(-dtv * __expf(A_log[d * 16 + j]));
                h[j] = h[j] * e + du * bc[t][j];
                p[j] *= e;
            }
        }
    }
    #pragma unroll
    for (int g = 0; g < 4; ++g) {
        f32x4 pv = {p[4*g+0], p[4*g+1], p[4*g+2], p[4*g+3]};
        f32x4 hv = {h[4*g+0], h[4*g+1], h[4*g+2], h[4*g+3]};
        *(f32x4*)&cP[c][dg][4 * g] = pv;
        *(f32x4*)&cH[c][dg][4 * g] = hv;
    }
    __syncthreads();
    // --- Hillis-Steele over 4 chunks (2 rounds, wave-uniform branch) ---
    #pragma unroll
    for (int s = 1; s < 4; s <<= 1) {
        f32x4 qv[4], gv[4];
        const bool act = (c >= s);
        if (act) {
            #pragma unroll
            for (int g = 0; g < 4; ++g) {
                qv[g] = *(const f32x4*)&cP[c - s][dg][4 * g];
                gv[g] = *(const f32x4*)&cH[c - s][dg][4 * g];
            }
        }
        __syncthreads();
        if (act) {
            #pragma unroll
            for (int g = 0; g < 4; ++g) {
                #pragma unroll
                for (int k = 0; k < 4; ++k) {
                    h[4*g+k] += p[4*g+k] * gv[g][k];
                    p[4*g+k] *= qv[g][k];
                }
                f32x4 pv = {p[4*g+0], p[4*g+1], p[4*g+2], p[4*g+3]};
                f32x4 hv = {h[4*g+0], h[4*g+1], h[4*g+2], h[4*g+3]};
                *(f32x4*)&cP[c][dg][4 * g] = pv;
                *(f32x4*)&cH[c][dg][4 * g] = hv;
            }
        }
        __syncthreads();
    }
    // entry state = inclusive prefix of chunk c-1
    #pragma unroll
    for (int g = 0; g < 4; ++g) {
        f32x4 ev = {0.f, 0.f, 0.f, 0.f};
        if (c > 0) ev = *(const f32x4*)&cH[c - 1][dg][4 * g];
        h[4*g+0] = ev[0]; h[4*g+1] = ev[1]; h[4*g+2] = ev[2]; h[4*g+3] = ev[3];
    }
    // --- pass 2: rescan from true entry state, emit y ---
    const float dpar = Dp[d];
    if (fast) {
        for (int i = 0; i < 32; ++i) {
            const int t = t0 + i;
            float dtv = (float)dtp[t * 512];
            float uv  = bf2f(up[t * 512]);
            float zv  = bf2f(zp[t * 512]);
            float du = dtv * uv;
            float E = __expf(-dtv);
            float E2 = E * E, E4 = E2 * E2, E8 = E4 * E4;
            float b1 = E4 * E, b2 = E8 * E, b3 = b2 * E4;
            f32x4 B0 = *(const f32x4*)&bc[t][0];
            f32x4 B1 = *(const f32x4*)&bc[t][4];
            f32x4 B2 = *(const f32x4*)&bc[t][8];
            f32x4 B3 = *(const f32x4*)&bc[t][12];
            f32x4 C0 = *(const f32x4*)&bc[t][16];
            f32x4 C1 = *(const f32x4*)&bc[t][20];
            f32x4 C2 = *(const f32x4*)&bc[t][24];
            f32x4 C3 = *(const f32x4*)&bc[t][28];
            float y = 0.f, e;
            e = E;  h[0] = h[0]*e + du*B0[0];  y += h[0]*C0[0];  e *= E; h[1] = h[1]*e + du*B0[1];  y += h[1]*C0[1];
            e *= E; h[2] = h[2]*e + du*B0[2];  y += h[2]*C0[2];  e *= E; h[3] = h[3]*e + du*B0[3];  y += h[3]*C0[3];
            e = b1; h[4] = h[4]*e + du*B1[0];  y += h[4]*C1[0];  e *= E; h[5] = h[5]*e + du*B1[1];  y += h[5]*C1[1];
            e *= E; h[6] = h[6]*e + du*B1[2];  y += h[6]*C1[2];  e *= E; h[7] = h[7]*e + du*B1[3];  y += h[7]*C1[3];
            e = b2; h[8] = h[8]*e + du*B2[0];  y += h[8]*C2[0];  e *= E; h[9] = h[9]*e + du*B2[1];  y += h[9]*C2[1];
            e *= E; h[10] = h[10]*e + du*B2[2]; y += h[10]*C2[2]; e *= E; h[11] = h[11]*e + du*B2[3]; y += h[11]*C2[3];
            e = b3; h[12] = h[12]*e + du*B3[0]; y += h[12]*C3[0]; e *= E; h[13] = h[13]*e + du*B3[1]; y += h[13]*C3[1];
            e *= E; h[14] = h[14]*e + du*B3[2]; y += h[14]*C3[2]; e *= E; h[15] = h[15]*e + du*B3[3]; y += h[15]*C3[3];
            float yf = (y + uv * dpar) * (zv / (1.f + __expf(-zv)));
            yp[t * 512] = f2bf(yf);
        }
    } else {
        for (int i = 0; i < 32; ++i) {
            const int t = t0 + i;
            float dtv = (float)dtp[t * 512];
            float uv  = bf2f(up[t * 512]);
            float zv  = bf2f(zp[t * 512]);
            float du = dtv * uv;
            float y = 0.f;
            #pragma unroll
            for (int j = 0; j < 16; ++j) {
                float e = __expf(-dtv * __expf(A_log[d * 16 + j]));
                h[j] = h[j] * e + du * bc[t][j];
                y += h[j] * bc[t][16 + j];
            }
            float yf = (y + uv * dpar) * (zv / (1.f + __expf(-zv)));
            yp[t * 512] = f2bf(yf);
        }
    }
}

// ---------------------------------------------------------------------------
// out = LayerNorm( y_bf[16384 x 512] @ W_out_bf[256 x 512]^T ) with permuted store.
__global__ __launch_bounds__(256, 2) void k_out_ln(const unsigned short* __restrict__ Y,
                                                   const unsigned short* __restrict__ Wb,
                                                   const float* __restrict__ gamma,
                                                   const float* __restrict__ beta,
                                                   float* __restrict__ out) {
    __shared__ float s_sum[32], s_sq[32];
    const int w = threadIdx.x >> 6, l = threadIdx.x & 63;
    const int lr = l & 15, lg = l >> 4;
    const int row0 = blockIdx.x * 32;
    const int n0 = w * 64;
    f32x4 acc[2][4] = {};
    for (int k0 = 0; k0 < 512; k0 += 32) {
        const int ka = k0 + lg * 8;
        bf16x8 a[2], b[4];
        #pragma unroll
        for (int mi = 0; mi < 2; ++mi)
            a[mi] = *(const bf16x8*)(Y + (size_t)(row0 + mi * 16 + lr) * 512 + ka);
        #pragma unroll
        for (int ni = 0; ni < 4; ++ni)
            b[ni] = *(const bf16x8*)(Wb + (size_t)(n0 + ni * 16 + lr) * 512 + ka);
        #pragma unroll
        for (int mi = 0; mi < 2; ++mi)
            #pragma unroll
            for (int ni = 0; ni < 4; ++ni)
                acc[mi][ni] = __builtin_amdgcn_mfma_f32_16x16x32_bf16(a[mi], b[ni], acc[mi][ni], 0, 0, 0);
    }
    if (threadIdx.x < 32) { s_sum[threadIdx.x] = 0.f; s_sq[threadIdx.x] = 0.f; }
    __syncthreads();
    #pragma unroll
    for (int mi = 0; mi < 2; ++mi)
        #pragma unroll
        for (int r = 0; r < 4; ++r) {
            float s = 0.f, q = 0.f;
            #pragma unroll
            for (int ni = 0; ni < 4; ++ni) { float v = acc[mi][ni][r]; s += v; q += v * v; }
            #pragma unroll
            for (int m = 1; m < 16; m <<= 1) { s += __shfl_xor(s, m, 64); q += __shfl_xor(q, m, 64); }
            if (lr == 0) {
                atomicAdd(&s_sum[mi * 16 + lg * 4 + r], s);
                atomicAdd(&s_sq[mi * 16 + lg * 4 + r], q);
            }
        }
    __syncthreads();
    float g[4], be[4];
    #pragma unroll
    for (int ni = 0; ni < 4; ++ni) {
        g[ni] = gamma[n0 + ni * 16 + lr];
        be[ni] = beta[n0 + ni * 16 + lr];
    }
    #pragma unroll
    for (int mi = 0; mi < 2; ++mi)
        #pragma unroll
        for (int r = 0; r < 4; ++r) {
            const int rl = mi * 16 + lg * 4 + r;
            const int row = row0 + rl;
            const float mu = s_sum[rl] * (1.f / 256.f);
            const float var = s_sq[rl] * (1.f / 256.f) - mu * mu;
            const float rs = rsqrtf(var + 1e-5f);
            const int t = row & 127, bn = row >> 7;
            const int nn = bn & 63, bb = bn >> 6;
            float* orow = out + ((((size_t)(bb * 128 + t)) * 64 + nn) << 8);
            #pragma unroll
            for (int ni = 0; ni < 4; ++ni)
                orow[n0 + ni * 16 + lr] = (acc[mi][ni][r] - mu) * rs * g[ni] + be[ni];
        }
}

// ---------------------------------------------------------------------------
extern "C" void kernel_launch(void* const* d_in, const int* in_sizes, int n_in,
                              void* d_out, int out_size, void* d_ws, size_t ws_size,
                              hipStream_t stream) {
    const float* x      = (const float*)d_in[0];
    const float* W_in   = (const float*)d_in[1];
    const float* W_conv = (const float*)d_in[2];
    const float* b_conv = (const float*)d_in[3];
    const float* W_xprj = (const float*)d_in[4];
    const float* W_dt   = (const float*)d_in[5];
    const float* b_dt   = (const float*)d_in[6];
    const float* A_log  = (const float*)d_in[7];
    const float* D_par  = (const float*)d_in[8];
    const float* W_out  = (const float*)d_in[9];
    const float* gamma  = (const float*)d_in[10];
    const float* beta   = (const float*)d_in[11];
    float* out = (float*)d_out;

    char* ws = (char*)d_ws;
    size_t off = 0;
    auto alloc = [&](size_t bytes) -> void* {
        void* p = ws + off;
        off += (bytes + 255) & ~(size_t)255;
        return p;
    };
    // --- overlay region: dead after k_xproj; dtb aliases it ---
    unsigned short* Xbf   = (unsigned short*)alloc(16384ull * 256 * 2);
    unsigned short* Winb  = (unsigned short*)alloc(1024ull * 256 * 2);
    unsigned short* Wxpb  = (unsigned short*)alloc(48ull * 512 * 2);
    unsigned short* xp    = (unsigned short*)alloc(16384ull * 512 * 2);
    // --- live to the end ---
    unsigned short* Woutb = (unsigned short*)alloc(256ull * 512 * 2);
    unsigned short* zb    = (unsigned short*)alloc(16384ull * 512 * 2);
    unsigned short* ub    = (unsigned short*)alloc(16384ull * 512 * 2);
    float*          xdbl  = (float*)alloc(16384ull * 48 * 4);
    unsigned short* yb    = (unsigned short*)alloc(16384ull * 512 * 2);
    _Float16*       dtb   = (_Float16*)(ws);  // alias over Xbf..xp (dead by then)
    if (off > ws_size) return;

    k_prep_x<<<4096, 256, 0, stream>>>(x, (unsigned int*)Xbf);
    k_f2bf<<<256, 256, 0, stream>>>(W_in, (unsigned int*)Winb, 65536);
    k_f2bf<<<24, 256, 0, stream>>>(W_xprj, (unsigned int*)Wxpb, 6144);
    k_f2bf<<<128, 256, 0, stream>>>(W_out, (unsigned int*)Woutb, 32768);
    k_gemm1<<<dim3(128, 8), 256, 0, stream>>>(Xbf, Winb, xp, zb);
    k_conv<<<16384, 256, 0, stream>>>(xp, W_conv, b_conv, (unsigned int*)ub);
    k_xproj<<<256, 256, 0, stream>>>(ub, Wxpb, xdbl);
    k_dt<<<32768, 256, 0, stream>>>(xdbl, W_dt, b_dt, dtb);
    k_scan<<<1024, 256, 0, stream>>>(dtb, xdbl, ub, zb, A_log, D_par, yb);
    k_out_ln<<<512, 256, 0, stream>>>(yb, Woutb, gamma, beta, out);
}

// Round 7
// 176.315 us; speedup vs baseline: 2.3177x; 1.0869x over previous
//
#include <hip/hip_runtime.h>

typedef short bf16x8 __attribute__((ext_vector_type(8)));
typedef float f32x4 __attribute__((ext_vector_type(4)));

__device__ __forceinline__ unsigned short f2bf(float f) {
    unsigned int u = __builtin_bit_cast(unsigned int, f);
    u = (u + 0x7FFFu + ((u >> 16) & 1u)) >> 16;
    return (unsigned short)u;
}
__device__ __forceinline__ float bf2f(unsigned short h) {
    unsigned int u = ((unsigned int)h) << 16;
    return __builtin_bit_cast(float, u);
}

// ---------------------------------------------------------------------------
// Prep: permute x (B,T,N,Dm) -> Xbf rows r = bn*128+t, bn = b*64+n; fp32->bf16
__global__ __launch_bounds__(256) void k_prep_x(const float* __restrict__ x,
                                                unsigned int* __restrict__ Xbf2) {
    int tid = blockIdx.x * 256 + threadIdx.x;
    int c4 = tid & 63;
    int r  = tid >> 6;
    int t = r & 127, bn = r >> 7;
    int n = bn & 63, b = bn >> 6;
    const float4 v = *((const float4*)(x + ((((size_t)(b * 128 + t)) * 64 + n) << 8)) + c4);
    uint2 o;
    o.x = (unsigned int)f2bf(v.x) | ((unsigned int)f2bf(v.y) << 16);
    o.y = (unsigned int)f2bf(v.z) | ((unsigned int)f2bf(v.w) << 16);
    *((uint2*)(Xbf2 + ((size_t)r << 7)) + c4) = o;
}

// Generic fp32 -> bf16 convert, 4 elements/thread (count % 4 == 0).
__global__ __launch_bounds__(256) void k_f2bf(const float* __restrict__ in,
                                              unsigned int* __restrict__ out, int n4) {
    int tid = blockIdx.x * 256 + threadIdx.x;
    if (tid >= n4) return;
    float4 v = ((const float4*)in)[tid];
    uint2 o;
    o.x = (unsigned int)f2bf(v.x) | ((unsigned int)f2bf(v.y) << 16);
    o.y = (unsigned int)f2bf(v.z) | ((unsigned int)f2bf(v.w) << 16);
    ((uint2*)out)[tid] = o;
}

// ---------------------------------------------------------------------------
// GEMM1: xz[16384 x 1024] = Xbf[16384 x 256] @ W_in_bf[1024 x 256]^T
// 128x128 tile, BK=64, double-buffered LDS, reg-staged, XOR-swizzled both sides.
__global__ __launch_bounds__(256, 2) void k_gemm1(const unsigned short* __restrict__ A,
                                                  const unsigned short* __restrict__ Bw,
                                                  unsigned short* __restrict__ xp,
                                                  unsigned short* __restrict__ z) {
    __shared__ unsigned short As[2][128][64];
    __shared__ unsigned short Bs[2][128][64];
    const int tid = threadIdx.x;
    const int l = tid & 63, w = tid >> 6;
    const int lr = l & 15, lg = l >> 4;
    const int wr = w >> 1, wc = w & 1;
    const int row0 = blockIdx.x * 128;
    const int n0b  = blockIdx.y * 128;

    bf16x8 sa[4], sb[4];
    auto LOAD = [&](int k0) {
        #pragma unroll
        for (int r2 = 0; r2 < 4; ++r2) {
            int cc = tid + r2 * 256;
            int row = cc >> 3, ke = (cc & 7) * 8;
            sa[r2] = *(const bf16x8*)(A  + (size_t)(row0 + row) * 256 + k0 + ke);
            sb[r2] = *(const bf16x8*)(Bw + (size_t)(n0b + row) * 256 + k0 + ke);
        }
    };
    auto WRITE = [&](int buf) {
        #pragma unroll
        for (int r2 = 0; r2 < 4; ++r2) {
            int cc = tid + r2 * 256;
            int row = cc >> 3, ke = (cc & 7) * 8;
            int ks = ke ^ ((row & 7) * 8);
            *(bf16x8*)&As[buf][row][ks] = sa[r2];
            *(bf16x8*)&Bs[buf][row][ks] = sb[r2];
        }
    };

    f32x4 acc[4][4] = {};
    LOAD(0); WRITE(0);
    __syncthreads();
    int cur = 0;
    for (int kt = 0; kt < 4; ++kt) {
        if (kt < 3) LOAD((kt + 1) * 64);
        #pragma unroll
        for (int ks = 0; ks < 2; ++ks) {
            const int ka = ks * 32;
            bf16x8 a[4], b[4];
            #pragma unroll
            for (int mi = 0; mi < 4; ++mi) {
                int row = wr * 64 + mi * 16 + lr;
                int e = (ka + lg * 8) ^ ((row & 7) * 8);
                a[mi] = *(const bf16x8*)&As[cur][row][e];
            }
            #pragma unroll
            for (int ni = 0; ni < 4; ++ni) {
                int row = wc * 64 + ni * 16 + lr;
                int e = (ka + lg * 8) ^ ((row & 7) * 8);
                b[ni] = *(const bf16x8*)&Bs[cur][row][e];
            }
            #pragma unroll
            for (int mi = 0; mi < 4; ++mi)
                #pragma unroll
                for (int ni = 0; ni < 4; ++ni)
                    acc[mi][ni] = __builtin_amdgcn_mfma_f32_16x16x32_bf16(a[mi], b[ni], acc[mi][ni], 0, 0, 0);
        }
        if (kt < 3) WRITE(cur ^ 1);
        __syncthreads();
        cur ^= 1;
    }
    const bool isz = (blockIdx.y >= 4);
    unsigned short* dst = isz ? z : xp;
    const int colbase = (blockIdx.y - (isz ? 4 : 0)) * 128 + wc * 64;
    #pragma unroll
    for (int mi = 0; mi < 4; ++mi)
        #pragma unroll
        for (int r = 0; r < 4; ++r) {
            const int row = row0 + wr * 64 + mi * 16 + lg * 4 + r;
            #pragma unroll
            for (int ni = 0; ni < 4; ++ni)
                dst[(size_t)row * 512 + colbase + ni * 16 + lr] = f2bf(acc[mi][ni][r]);
        }
}

// ---------------------------------------------------------------------------
// Depthwise causal conv(4) + bias + SiLU, fully parallel over (bn, t, d-pair).
__global__ __launch_bounds__(256) void k_conv(const unsigned short* __restrict__ xp,
                                              const float* __restrict__ Wc,
                                              const float* __restrict__ bcv,
                                              unsigned int* __restrict__ ub2) {
    int tid = blockIdx.x * 256 + threadIdx.x;
    int d2 = tid & 255, r = tid >> 8;
    int t = r & 127, bn = r >> 7;
    int d = d2 << 1;
    const unsigned short* src = xp + (size_t)bn * 65536 + d;
    f32x4 wa = *(const f32x4*)(Wc + d * 4);
    f32x4 wb = *(const f32x4*)(Wc + d * 4 + 4);
    float a0 = bcv[d], a1 = bcv[d + 1];
    #pragma unroll
    for (int k = 0; k < 4; ++k) {
        int tt = t - 3 + k;
        if (tt >= 0) {
            unsigned int p = *(const unsigned int*)(src + (size_t)tt * 512);
            a0 += bf2f((unsigned short)(p & 0xFFFFu)) * wa[k];
            a1 += bf2f((unsigned short)(p >> 16)) * wb[k];
        }
    }
    float u0 = a0 / (1.f + __expf(-a0));
    float u1 = a1 / (1.f + __expf(-a1));
    ub2[((size_t)bn * 65536 + (size_t)t * 512 + d) >> 1] =
        (unsigned int)f2bf(u0) | ((unsigned int)f2bf(u1) << 16);
}

// ---------------------------------------------------------------------------
// x_dbl[16384 x 48] = u_bf[16384 x 512] @ W_xproj_bf[48 x 512]^T  (fp32 out)
__global__ __launch_bounds__(256, 2) void k_xproj(const unsigned short* __restrict__ U,
                                                  const unsigned short* __restrict__ Wb,
                                                  float* __restrict__ xdbl) {
    const int w = threadIdx.x >> 6, l = threadIdx.x & 63;
    const int lr = l & 15, lg = l >> 4;
    const int row0 = blockIdx.x * 64 + w * 16;
    f32x4 acc[3] = {};
    for (int k0 = 0; k0 < 512; k0 += 32) {
        const int ka = k0 + lg * 8;
        bf16x8 a = *(const bf16x8*)(U + (size_t)(row0 + lr) * 512 + ka);
        bf16x8 b[3];
        #pragma unroll
        for (int ni = 0; ni < 3; ++ni)
            b[ni] = *(const bf16x8*)(Wb + (size_t)(ni * 16 + lr) * 512 + ka);
        #pragma unroll
        for (int ni = 0; ni < 3; ++ni)
            acc[ni] = __builtin_amdgcn_mfma_f32_16x16x32_bf16(a, b[ni], acc[ni], 0, 0, 0);
    }
    #pragma unroll
    for (int r = 0; r < 4; ++r) {
        const int row = row0 + lg * 4 + r;
        #pragma unroll
        for (int ni = 0; ni < 3; ++ni)
            xdbl[(size_t)row * 48 + ni * 16 + lr] = acc[ni][r];
    }
}

// ---------------------------------------------------------------------------
// dt = softplus(dt_raw @ W_dt^T + b_dt), fully parallel. One thread per (r, d).
__global__ __launch_bounds__(256) void k_dt(const float* __restrict__ xdbl,
                                            const float* __restrict__ W_dt,
                                            const float* __restrict__ b_dt,
                                            _Float16* __restrict__ dtb) {
    int tid = blockIdx.x * 256 + threadIdx.x;
    int d = tid & 511, r = tid >> 9;
    const f32x4* xr = (const f32x4*)(xdbl + (size_t)r * 48);
    const f32x4* wd = (const f32x4*)(W_dt + d * 16);
    float dl = b_dt[d];
    #pragma unroll
    for (int k = 0; k < 4; ++k) {
        f32x4 xv = xr[k], wv = wd[k];
        dl += xv[0] * wv[0] + xv[1] * wv[1] + xv[2] * wv[2] + xv[3] * wv[3];
    }
    // softplus via HW v_exp/v_log (log1pf is a slow libm path); for very
    // negative dl, log(1+e^dl)~e^dl tiny -> contribution negligible.
    float dt = (dl > 20.f) ? dl : __logf(1.f + __expf(dl));
    dtb[(size_t)r * 512 + d] = (_Float16)dt;
}

// ---------------------------------------------------------------------------
// Chunked parallel selective scan v5.
// Block = 256 thr = 4 chunks(T=32) x 64 d; grid = 128 bn x 8 = 1024 blocks.
// R6 fixes: (1) combine arrays transposed to _Float16 [3][16][64] -- lane-
// consecutive halfs = conflict-free (was stride-16 f32 = 16-way, 2.4M conflict
// cycles); LDS 48->28 KB -> 5 blocks/CU so the 4-blocks/CU grid is fully
// co-resident. (2) Flattened power ladder (depth ~4 instead of serial-16).
// (3) Chunk 3 skips pass 1 + combine (its local (P,H) is never consumed).
// (4) Tree-reduced y-dot. Fast path requires A_j = -(j+1) (runtime-verified);
// generic fallback keeps data-independence.
__global__ __launch_bounds__(256, 5) void k_scan(const _Float16* __restrict__ dtb,
                                                 const float* __restrict__ xdbl,
                                                 const unsigned short* __restrict__ ub,
                                                 const unsigned short* __restrict__ zb,
                                                 const float* __restrict__ A_log,
                                                 const float* __restrict__ Dp,
                                                 unsigned short* __restrict__ yb) {
    __shared__ float bc[128][32];        // [t][ B(0..15) | C(16..31) ]  16 KB
    __shared__ _Float16 cP[3][16][64];   // [chunk][state][dg]            6 KB
    __shared__ _Float16 cH[3][16][64];   //                               6 KB
    const int bn = blockIdx.x >> 3;
    const int d0 = (blockIdx.x & 7) * 64;
    {   // stage B,C for this bn
        const float* src = xdbl + (size_t)(bn * 128) * 48 + 16;
        #pragma unroll
        for (int k = 0; k < 4; ++k) {
            int li = threadIdx.x + k * 256;
            int row = li >> 3, c4 = li & 7;
            *(f32x4*)(&bc[row][c4 * 4]) = *(const f32x4*)(src + row * 48 + c4 * 4);
        }
    }
    const int dg = threadIdx.x & 63;
    const int c  = threadIdx.x >> 6;   // chunk == wave id
    const int d  = d0 + dg;
    bool fast = true;
    #pragma unroll
    for (int j = 0; j < 16; ++j) {
        float aj = __expf(A_log[d * 16 + j]);
        fast = fast && (fabsf(aj - (float)(j + 1)) < 1e-3f * (float)(j + 1));
    }
    const _Float16* dtp = dtb + (size_t)(bn * 128) * 512 + d;
    const unsigned short* up = ub + (size_t)bn * 65536 + d;
    const unsigned short* zp = zb + (size_t)bn * 65536 + d;
    unsigned short* yp = yb + (size_t)bn * 65536 + d;
    const int t0 = c * 32;
    float h[16], p[16];
    #pragma unroll
    for (int j = 0; j < 16; ++j) { h[j] = 0.f; p[j] = 1.f; }
    __syncthreads();
    // --- pass 1: local scan (h0=0) + chunk product; chunks 0..2 only ---
    if (c < 3) {
        if (fast) {
            float S = 1.f;
            for (int i = 0; i < 32; ++i) {
                const int t = t0 + i;
                float dtv = (float)dtp[t * 512];
                float du  = dtv * bf2f(up[t * 512]);
                float E = __expf(-dtv);
                S *= E;
                float E2 = E * E, E3 = E2 * E, E4 = E2 * E2;
                float E8 = E4 * E4, E12 = E8 * E4;
                f32x4 B0 = *(const f32x4*)&bc[t][0];
                f32x4 B1 = *(const f32x4*)&bc[t][4];
                f32x4 B2 = *(const f32x4*)&bc[t][8];
                f32x4 B3 = *(const f32x4*)&bc[t][12];
                h[0]  = h[0]  * E         + du * B0[0];
                h[1]  = h[1]  * E2        + du * B0[1];
                h[2]  = h[2]  * E3        + du * B0[2];
                h[3]  = h[3]  * E4        + du * B0[3];
                h[4]  = h[4]  * (E4 * E)  + du * B1[0];
                h[5]  = h[5]  * (E4 * E2) + du * B1[1];
                h[6]  = h[6]  * (E4 * E3) + du * B1[2];
                h[7]  = h[7]  * E8        + du * B1[3];
                h[8]  = h[8]  * (E8 * E)  + du * B2[0];
                h[9]  = h[9]  * (E8 * E2) + du * B2[1];
                h[10] = h[10] * (E8 * E3) + du * B2[2];
                h[11] = h[11] * E12       + du * B2[3];
                h[12] = h[12] * (E12 * E) + du * B3[0];
                h[13] = h[13] * (E12 * E2)+ du * B3[1];
                h[14] = h[14] * (E12 * E3)+ du * B3[2];
                h[15] = h[15] * (E12 * E4)+ du * B3[3];
            }
            float S2 = S * S, S3 = S2 * S, S4 = S2 * S2;
            float S8 = S4 * S4, S12 = S8 * S4;
            p[0] = S;        p[1] = S2;        p[2] = S3;        p[3] = S4;
            p[4] = S4 * S;   p[5] = S4 * S2;   p[6] = S4 * S3;   p[7] = S8;
            p[8] = S8 * S;   p[9] = S8 * S2;   p[10] = S8 * S3;  p[11] = S12;
            p[12] = S12 * S; p[13] = S12 * S2; p[14] = S12 * S3; p[15] = S12 * S4;
        } else {
            for (int i = 0; i < 32; ++i) {
                const int t = t0 + i;
                float dtv = (float)dtp[t * 512];
                float du  = dtv * bf2f(up[t * 512]);
                #pragma unroll
                for (int j = 0; j < 16; ++j) {
                    float e = __expf(-dtv * __expf(A_log[d * 16 + j]));
                    h[j] = h[j] * e + du * bc[t][j];
                    p[j] *= e;
                }
            }
        }
        #pragma unroll
        for (int s = 0; s < 16; ++s) {
            cP[c][s][dg] = (_Float16)p[s];
            cH[c][s][dg] = (_Float16)h[s];
        }
    }
    __syncthreads();
    // --- Hillis-Steele over chunks 0..2 (2 rounds, wave-uniform) ---
    #pragma unroll
    for (int s = 1; s < 4; s <<= 1) {
        float qv[16], gv[16];
        const bool act = (c >= s) && (c < 3);
        if (act) {
            #pragma unroll
            for (int k = 0; k < 16; ++k) {
                qv[k] = (float)cP[c - s][k][dg];
                gv[k] = (float)cH[c - s][k][dg];
            }
        }
        __syncthreads();
        if (act) {
            #pragma unroll
            for (int k = 0; k < 16; ++k) {
                h[k] += p[k] * gv[k];
                p[k] *= qv[k];
                cP[c][k][dg] = (_Float16)p[k];
                cH[c][k][dg] = (_Float16)h[k];
            }
        }
        __syncthreads();
    }
    // entry state = inclusive prefix of chunk c-1
    #pragma unroll
    for (int j = 0; j < 16; ++j) h[j] = 0.f;
    if (c > 0) {
        #pragma unroll
        for (int j = 0; j < 16; ++j) h[j] = (float)cH[c - 1][j][dg];
    }
    // --- pass 2: rescan from true entry state, emit y ---
    const float dpar = Dp[d];
    if (fast) {
        for (int i = 0; i < 32; ++i) {
            const int t = t0 + i;
            float dtv = (float)dtp[t * 512];
            float uv  = bf2f(up[t * 512]);
            float zv  = bf2f(zp[t * 512]);
            float du = dtv * uv;
            float E = __expf(-dtv);
            float E2 = E * E, E3 = E2 * E, E4 = E2 * E2;
            float E8 = E4 * E4, E12 = E8 * E4;
            f32x4 B0 = *(const f32x4*)&bc[t][0];
            f32x4 B1 = *(const f32x4*)&bc[t][4];
            f32x4 B2 = *(const f32x4*)&bc[t][8];
            f32x4 B3 = *(const f32x4*)&bc[t][12];
            f32x4 C0 = *(const f32x4*)&bc[t][16];
            f32x4 C1 = *(const f32x4*)&bc[t][20];
            f32x4 C2 = *(const f32x4*)&bc[t][24];
            f32x4 C3 = *(const f32x4*)&bc[t][28];
            h[0]  = h[0]  * E         + du * B0[0];
            h[1]  = h[1]  * E2        + du * B0[1];
            h[2]  = h[2]  * E3        + du * B0[2];
            h[3]  = h[3]  * E4        + du * B0[3];
            h[4]  = h[4]  * (E4 * E)  + du * B1[0];
            h[5]  = h[5]  * (E4 * E2) + du * B1[1];
            h[6]  = h[6]  * (E4 * E3) + du * B1[2];
            h[7]  = h[7]  * E8        + du * B1[3];
            h[8]  = h[8]  * (E8 * E)  + du * B2[0];
            h[9]  = h[9]  * (E8 * E2) + du * B2[1];
            h[10] = h[10] * (E8 * E3) + du * B2[2];
            h[11] = h[11] * E12       + du * B2[3];
            h[12] = h[12] * (E12 * E) + du * B3[0];
            h[13] = h[13] * (E12 * E2)+ du * B3[1];
            h[14] = h[14] * (E12 * E3)+ du * B3[2];
            h[15] = h[15] * (E12 * E4)+ du * B3[3];
            float y0 = h[0] * C0[0] + h[1] * C0[1] + h[2] * C0[2] + h[3] * C0[3];
            float y1 = h[4] * C1[0] + h[5] * C1[1] + h[6] * C1[2] + h[7] * C1[3];
            float y2 = h[8] * C2[0] + h[9] * C2[1] + h[10] * C2[2] + h[11] * C2[3];
            float y3 = h[12] * C3[0] + h[13] * C3[1] + h[14] * C3[2] + h[15] * C3[3];
            float y = (y0 + y1) + (y2 + y3);
            float yf = (y + uv * dpar) * (zv / (1.f + __expf(-zv)));
            yp[t * 512] = f2bf(yf);
        }
    } else {
        for (int i = 0; i < 32; ++i) {
            const int t = t0 + i;
            float dtv = (float)dtp[t * 512];
            float uv  = bf2f(up[t * 512]);
            float zv  = bf2f(zp[t * 512]);
            float du = dtv * uv;
            float y = 0.f;
            #pragma unroll
            for (int j = 0; j < 16; ++j) {
                float e = __expf(-dtv * __expf(A_log[d * 16 + j]));
                h[j] = h[j] * e + du * bc[t][j];
                y += h[j] * bc[t][16 + j];
            }
            float yf = (y + uv * dpar) * (zv / (1.f + __expf(-zv)));
            yp[t * 512] = f2bf(yf);
        }
    }
}

// ---------------------------------------------------------------------------
// out = LayerNorm( y_bf[16384 x 512] @ W_out_bf[256 x 512]^T ) with permuted store.
__global__ __launch_bounds__(256, 2) void k_out_ln(const unsigned short* __restrict__ Y,
                                                   const unsigned short* __restrict__ Wb,
                                                   const float* __restrict__ gamma,
                                                   const float* __restrict__ beta,
                                                   float* __restrict__ out) {
    __shared__ float s_sum[32], s_sq[32];
    const int w = threadIdx.x >> 6, l = threadIdx.x & 63;
    const int lr = l & 15, lg = l >> 4;
    const int row0 = blockIdx.x * 32;
    const int n0 = w * 64;
    f32x4 acc[2][4] = {};
    for (int k0 = 0; k0 < 512; k0 += 32) {
        const int ka = k0 + lg * 8;
        bf16x8 a[2], b[4];
        #pragma unroll
        for (int mi = 0; mi < 2; ++mi)
            a[mi] = *(const bf16x8*)(Y + (size_t)(row0 + mi * 16 + lr) * 512 + ka);
        #pragma unroll
        for (int ni = 0; ni < 4; ++ni)
            b[ni] = *(const bf16x8*)(Wb + (size_t)(n0 + ni * 16 + lr) * 512 + ka);
        #pragma unroll
        for (int mi = 0; mi < 2; ++mi)
            #pragma unroll
            for (int ni = 0; ni < 4; ++ni)
                acc[mi][ni] = __builtin_amdgcn_mfma_f32_16x16x32_bf16(a[mi], b[ni], acc[mi][ni], 0, 0, 0);
    }
    if (threadIdx.x < 32) { s_sum[threadIdx.x] = 0.f; s_sq[threadIdx.x] = 0.f; }
    __syncthreads();
    #pragma unroll
    for (int mi = 0; mi < 2; ++mi)
        #pragma unroll
        for (int r = 0; r < 4; ++r) {
            float s = 0.f, q = 0.f;
            #pragma unroll
            for (int ni = 0; ni < 4; ++ni) { float v = acc[mi][ni][r]; s += v; q += v * v; }
            #pragma unroll
            for (int m = 1; m < 16; m <<= 1) { s += __shfl_xor(s, m, 64); q += __shfl_xor(q, m, 64); }
            if (lr == 0) {
                atomicAdd(&s_sum[mi * 16 + lg * 4 + r], s);
                atomicAdd(&s_sq[mi * 16 + lg * 4 + r], q);
            }
        }
    __syncthreads();
    float g[4], be[4];
    #pragma unroll
    for (int ni = 0; ni < 4; ++ni) {
        g[ni] = gamma[n0 + ni * 16 + lr];
        be[ni] = beta[n0 + ni * 16 + lr];
    }
    #pragma unroll
    for (int mi = 0; mi < 2; ++mi)
        #pragma unroll
        for (int r = 0; r < 4; ++r) {
            const int rl = mi * 16 + lg * 4 + r;
            const int row = row0 + rl;
            const float mu = s_sum[rl] * (1.f / 256.f);
            const float var = s_sq[rl] * (1.f / 256.f) - mu * mu;
            const float rs = rsqrtf(var + 1e-5f);
            const int t = row & 127, bn = row >> 7;
            const int nn = bn & 63, bb = bn >> 6;
            float* orow = out + ((((size_t)(bb * 128 + t)) * 64 + nn) << 8);
            #pragma unroll
            for (int ni = 0; ni < 4; ++ni)
                orow[n0 + ni * 16 + lr] = (acc[mi][ni][r] - mu) * rs * g[ni] + be[ni];
        }
}

// ---------------------------------------------------------------------------
extern "C" void kernel_launch(void* const* d_in, const int* in_sizes, int n_in,
                              void* d_out, int out_size, void* d_ws, size_t ws_size,
                              hipStream_t stream) {
    const float* x      = (const float*)d_in[0];
    const float* W_in   = (const float*)d_in[1];
    const float* W_conv = (const float*)d_in[2];
    const float* b_conv = (const float*)d_in[3];
    const float* W_xprj = (const float*)d_in[4];
    const float* W_dt   = (const float*)d_in[5];
    const float* b_dt   = (const float*)d_in[6];
    const float* A_log  = (const float*)d_in[7];
    const float* D_par  = (const float*)d_in[8];
    const float* W_out  = (const float*)d_in[9];
    const float* gamma  = (const float*)d_in[10];
    const float* beta   = (const float*)d_in[11];
    float* out = (float*)d_out;

    char* ws = (char*)d_ws;
    size_t off = 0;
    auto alloc = [&](size_t bytes) -> void* {
        void* p = ws + off;
        off += (bytes + 255) & ~(size_t)255;
        return p;
    };
    // --- overlay region: dead after k_xproj; dtb aliases it ---
    unsigned short* Xbf   = (unsigned short*)alloc(16384ull * 256 * 2);
    unsigned short* Winb  = (unsigned short*)alloc(1024ull * 256 * 2);
    unsigned short* Wxpb  = (unsigned short*)alloc(48ull * 512 * 2);
    unsigned short* xp    = (unsigned short*)alloc(16384ull * 512 * 2);
    // --- live to the end ---
    unsigned short* Woutb = (unsigned short*)alloc(256ull * 512 * 2);
    unsigned short* zb    = (unsigned short*)alloc(16384ull * 512 * 2);
    unsigned short* ub    = (unsigned short*)alloc(16384ull * 512 * 2);
    float*          xdbl  = (float*)alloc(16384ull * 48 * 4);
    unsigned short* yb    = (unsigned short*)alloc(16384ull * 512 * 2);
    _Float16*       dtb   = (_Float16*)(ws);  // alias over Xbf..xp (dead by then)
    if (off > ws_size) return;

    k_prep_x<<<4096, 256, 0, stream>>>(x, (unsigned int*)Xbf);
    k_f2bf<<<256, 256, 0, stream>>>(W_in, (unsigned int*)Winb, 65536);
    k_f2bf<<<24, 256, 0, stream>>>(W_xprj, (unsigned int*)Wxpb, 6144);
    k_f2bf<<<128, 256, 0, stream>>>(W_out, (unsigned int*)Woutb, 32768);
    k_gemm1<<<dim3(128, 8), 256, 0, stream>>>(Xbf, Winb, xp, zb);
    k_conv<<<16384, 256, 0, stream>>>(xp, W_conv, b_conv, (unsigned int*)ub);
    k_xproj<<<256, 256, 0, stream>>>(ub, Wxpb, xdbl);
    k_dt<<<32768, 256, 0, stream>>>(xdbl, W_dt, b_dt, dtb);
    k_scan<<<1024, 256, 0, stream>>>(dtb, xdbl, ub, zb, A_log, D_par, yb);
    k_out_ln<<<512, 256, 0, stream>>>(yb, Woutb, gamma, beta, out);
}